// Round 8
// baseline (23181.621 us; speedup 1.0000x reference)
//
#include <hip/hip_runtime.h>

#define KN 32768
#define KE 65536
#define KB 512

/* workspace element offsets */
#define O_BUF0 ((size_t)0)
#define O_BUF1 (O_BUF0 + (size_t)KN * 64)
#define O_DEG  (O_BUF1 + (size_t)KN * 64)
#define O_GCNT (O_DEG + KN)
#define O_GST  (O_GCNT + KB)
#define O_FLAG (O_GST + KB + 8)
#define O_ZEND (O_GST + KB + 64)

__device__ float sigf(float x) { return 1.0f / (1.0f + expf(-x)); }

/* diagnostic fill (f32 output!) */
extern "C" __global__ void GNNModule_9259949490279_kernel(float* out, float v) {
    int i = blockIdx.x * 256 + threadIdx.x;
    if (i < KB * 64) out[i] = v;
}

/* flag -> distinctive output (no-op when flag==0) */
extern "C" __global__ void k_post(const int* flag, float* out) {
    int f = flag[0];
    if (f == 0) return;
    int i = blockIdx.x * 256 + threadIdx.x;
    if (i < KB * 64) out[i] = 300.0f + (float)f;
}

extern "C" __global__ void k_zero(float* ws) {
    size_t i = (size_t)blockIdx.x * 256 + threadIdx.x;
    size_t stride = (size_t)gridDim.x * 256;
    for (size_t p = i; p < O_ZEND; p += stride) ws[p] = 0.0f;
}

extern "C" __global__ void k_deg(const int* dst, float* deg, int* flag) {
    int e = blockIdx.x * 256 + threadIdx.x;
    if (e >= KE) return;
    int d = dst[e];
    if ((unsigned)d >= (unsigned)KN) { atomicOr(flag, 1); d = 0; }
    atomicAdd(&deg[d], 1.0f);
}

extern "C" __global__ void k_gcount(const int* gid, int* gcnt, int* flag) {
    int n = blockIdx.x * 256 + threadIdx.x;
    if (n >= KN) return;
    int g = gid[n];
    if ((unsigned)g >= (unsigned)KB) { atomicOr(flag, 2); g = 0; }
    atomicAdd(&gcnt[g], 1);
}

/* single block, 64 threads: exclusive scan of 512 counts */
extern "C" __global__ void k_gscan(const int* gcnt, int* gstart) {
    __shared__ int part[64];
    __shared__ int pre[64];
    int t = threadIdx.x;
    int v[8];
    int s = 0;
    int base = t * 8;
    for (int j = 0; j < 8; ++j) { v[j] = gcnt[base + j]; s += v[j]; }
    part[t] = s;
    __syncthreads();
    if (t == 0) {
        int run = 0;
        for (int i = 0; i < 64; ++i) { pre[i] = run; run += part[i]; }
    }
    __syncthreads();
    int run = pre[t];
    for (int j = 0; j < 8; ++j) { gstart[base + j] = run; run += v[j]; }
    if (t == 63) gstart[KB] = run;
}

/* direct NNConv: block = 64 consecutive edges, 256 threads.
   m[e,o] = sum_i x[src_e,i] * ( sum_k relu(ef_e*ew1_k+eb1_k)*ew2[i*64+o,k] + eb2[i*64+o] ) */
extern "C" __global__ void k_conv(
    const float* x, const float* efeat, const int* src, const int* dst,
    const float* ew1, const float* eb1, const float* ew2, const float* eb2,
    float* sbuf, int* flag) {
    __shared__ float efs[64];
    __shared__ int sj[64];
    __shared__ int dj[64];
    __shared__ float hh[2048];      /* h[j][k], j=edge 0..63, k=0..31 */
    __shared__ float xs[4096];      /* x[src_j][i] */
    __shared__ float we2[8448];     /* tile [256][33] padded */
    __shared__ float ebt[256];

    int t = threadIdx.x;
    int e0 = blockIdx.x * 64;
    if (t < 64) {
        int sv = src[e0 + t];
        int dv = dst[e0 + t];
        if ((unsigned)sv >= (unsigned)KN) { atomicOr(flag, 4); sv = 0; }
        if ((unsigned)dv >= (unsigned)KN) { atomicOr(flag, 4); dv = 0; }
        efs[t] = efeat[e0 + t];
        sj[t] = sv;
        dj[t] = dv;
    }
    __syncthreads();
    for (int u = t; u < 2048; u += 256) {
        int j = u >> 5;
        int k = u & 31;
        float hv = efs[j] * ew1[k] + eb1[k];
        hh[u] = (hv > 0.0f) ? hv : 0.0f;
    }
    for (int u = t; u < 4096; u += 256) {
        int j = u >> 6;
        int i = u & 63;
        xs[u] = x[(size_t)sj[j] * 64 + i];
    }

    int lane = t & 63;
    int wj = t >> 6;
    float acc[16];
    for (int j = 0; j < 16; ++j) acc[j] = 0.0f;

    for (int tau = 0; tau < 16; ++tau) {
        __syncthreads();
        for (int u = t; u < 8192; u += 256) {
            int r = u >> 5;
            int k = u & 31;
            we2[r * 33 + k] = ew2[(size_t)tau * 8192 + u];
        }
        ebt[t] = eb2[tau * 256 + t];
        __syncthreads();
        for (int ip = 0; ip < 4; ++ip) {
            float w[32];
            int rbase = (ip * 64 + lane) * 33;
            for (int k = 0; k < 32; ++k) w[k] = we2[rbase + k];
            float eb = ebt[ip * 64 + lane];
            int i = tau * 4 + ip;
            for (int j16 = 0; j16 < 16; ++j16) {
                int j = wj * 16 + j16;
                float s = 0.0f;
                for (int k = 0; k < 32; ++k) s += hh[j * 32 + k] * w[k];
                acc[j16] += xs[j * 64 + i] * (s + eb);
            }
        }
    }
    for (int j16 = 0; j16 < 16; ++j16) {
        int j = wj * 16 + j16;
        atomicAdd(&sbuf[(size_t)dj[j] * 64 + lane], acc[j16]);
    }
}

extern "C" __global__ void k_final0(float* s, const float* deg, const float* cb, int* flag) {
    int idx = blockIdx.x * 256 + threadIdx.x;
    int n = idx >> 6;
    int o = idx & 63;
    float d = deg[n];
    if (d < 1.0f) d = 1.0f;
    float v = s[idx] / d + cb[o];
    if (v < 0.0f) v = 0.0f;
    if (!(v == v)) { v = 0.0f; atomicOr(flag, 32); }
    s[idx] = v;
}

/* one node per block, 64 threads, LDS reductions */
extern "C" __global__ void k_final1ln(float* s, const float* deg, const float* cb,
                                      const float* lg, const float* lb, int* flag) {
    __shared__ float red[64];
    int t = threadIdx.x;
    int n = blockIdx.x;
    float d = deg[n];
    if (d < 1.0f) d = 1.0f;
    float v = s[(size_t)n * 64 + t] / d + cb[t];
    if (v < 0.0f) v = 0.0f;
    red[t] = v;
    __syncthreads();
    for (int m = 32; m >= 1; m >>= 1) {
        if (t < m) red[t] += red[t + m];
        __syncthreads();
    }
    float mu = red[0] * (1.0f / 64.0f);
    __syncthreads();
    red[t] = v * v;
    __syncthreads();
    for (int m = 32; m >= 1; m >>= 1) {
        if (t < m) red[t] += red[t + m];
        __syncthreads();
    }
    float var = red[0] * (1.0f / 64.0f) - mu * mu;
    float rs = rsqrtf(var + 1e-5f);
    float r = (v - mu) * rs * lg[t] + lb[t];
    if (!(r == r)) { r = 0.0f; atomicOr(flag, 8); }
    s[(size_t)n * 64 + t] = r;
}

/* one graph per block, 64 threads. Set2Set (6 iters, 3-layer LSTM) + head. */
extern "C" __global__ void k_s2s(
    const float* x, const int* gstart,
    const float* wih0, const float* whh0, const float* bih0, const float* bhh0,
    const float* wih1, const float* whh1, const float* bih1, const float* bhh1,
    const float* wih2, const float* whh2, const float* bih2, const float* bhh2,
    const float* gn_g, const float* gn_b,
    const float* fc1_w, const float* fc1_b,
    const float* bn_g, const float* bn_b, const float* bn_m, const float* bn_v,
    const float* fc2_w, const float* fc2_b,
    float* out, int* flag) {
    __shared__ float qs[128];
    __shared__ float hh0[64];
    __shared__ float hh1[64];
    __shared__ float hh2[64];
    __shared__ float esc[1024];
    __shared__ float red[64];
    __shared__ float scr[128];
    int t = threadIdx.x;
    int g = blockIdx.x;

    qs[t] = 0.0f;
    qs[64 + t] = 0.0f;
    hh0[t] = 0.0f;
    hh1[t] = 0.0f;
    hh2[t] = 0.0f;
    float c0 = 0.0f, c1 = 0.0f, c2 = 0.0f;
    __syncthreads();

    int n0 = gstart[g];
    int n1 = gstart[g + 1];
    if (n0 < 0) n0 = 0;
    if (n0 > KN) n0 = KN;
    if (n1 < n0) n1 = n0;
    if (n1 > KN) n1 = KN;
    int cnt = n1 - n0;
    if (cnt > 1024) { cnt = 1024; if (t == 0) atomicOr(flag, 16); }

    for (int it = 0; it < 6; ++it) {
        /* LSTM cell 0: input qs (K=128), hidden hh0 */
        {
            float gi = bih0[t] + bhh0[t];
            float gf = bih0[64 + t] + bhh0[64 + t];
            float gg = bih0[128 + t] + bhh0[128 + t];
            float go = bih0[192 + t] + bhh0[192 + t];
            for (int k = 0; k < 128; ++k) {
                float v = qs[k];
                gi += wih0[(size_t)t * 128 + k] * v;
                gf += wih0[(size_t)(64 + t) * 128 + k] * v;
                gg += wih0[(size_t)(128 + t) * 128 + k] * v;
                go += wih0[(size_t)(192 + t) * 128 + k] * v;
            }
            for (int k = 0; k < 64; ++k) {
                float v = hh0[k];
                gi += whh0[(size_t)t * 64 + k] * v;
                gf += whh0[(size_t)(64 + t) * 64 + k] * v;
                gg += whh0[(size_t)(128 + t) * 64 + k] * v;
                go += whh0[(size_t)(192 + t) * 64 + k] * v;
            }
            c0 = sigf(gf) * c0 + sigf(gi) * tanhf(gg);
            float hn = sigf(go) * tanhf(c0);
            __syncthreads();
            hh0[t] = hn;
            __syncthreads();
        }
        /* LSTM cell 1: input hh0 (K=64), hidden hh1 */
        {
            float gi = bih1[t] + bhh1[t];
            float gf = bih1[64 + t] + bhh1[64 + t];
            float gg = bih1[128 + t] + bhh1[128 + t];
            float go = bih1[192 + t] + bhh1[192 + t];
            for (int k = 0; k < 64; ++k) {
                float v = hh0[k];
                gi += wih1[(size_t)t * 64 + k] * v;
                gf += wih1[(size_t)(64 + t) * 64 + k] * v;
                gg += wih1[(size_t)(128 + t) * 64 + k] * v;
                go += wih1[(size_t)(192 + t) * 64 + k] * v;
            }
            for (int k = 0; k < 64; ++k) {
                float v = hh1[k];
                gi += whh1[(size_t)t * 64 + k] * v;
                gf += whh1[(size_t)(64 + t) * 64 + k] * v;
                gg += whh1[(size_t)(128 + t) * 64 + k] * v;
                go += whh1[(size_t)(192 + t) * 64 + k] * v;
            }
            c1 = sigf(gf) * c1 + sigf(gi) * tanhf(gg);
            float hn = sigf(go) * tanhf(c1);
            __syncthreads();
            hh1[t] = hn;
            __syncthreads();
        }
        /* LSTM cell 2: input hh1 (K=64), hidden hh2 */
        {
            float gi = bih2[t] + bhh2[t];
            float gf = bih2[64 + t] + bhh2[64 + t];
            float gg = bih2[128 + t] + bhh2[128 + t];
            float go = bih2[192 + t] + bhh2[192 + t];
            for (int k = 0; k < 64; ++k) {
                float v = hh1[k];
                gi += wih2[(size_t)t * 64 + k] * v;
                gf += wih2[(size_t)(64 + t) * 64 + k] * v;
                gg += wih2[(size_t)(128 + t) * 64 + k] * v;
                go += wih2[(size_t)(192 + t) * 64 + k] * v;
            }
            for (int k = 0; k < 64; ++k) {
                float v = hh2[k];
                gi += whh2[(size_t)t * 64 + k] * v;
                gf += whh2[(size_t)(64 + t) * 64 + k] * v;
                gg += whh2[(size_t)(128 + t) * 64 + k] * v;
                go += whh2[(size_t)(192 + t) * 64 + k] * v;
            }
            c2 = sigf(gf) * c2 + sigf(gi) * tanhf(gg);
            float hn = sigf(go) * tanhf(c2);
            __syncthreads();
            hh2[t] = hn;
            __syncthreads();
        }
        /* attention over this graph's nodes */
        float mx = -1e30f;
        for (int p = t; p < cnt; p += 64) {
            size_t base = (size_t)(n0 + p) * 64;
            float a = 0.0f;
            for (int k = 0; k < 64; ++k) a += x[base + k] * hh2[k];
            esc[p] = a;
            if (a > mx) mx = a;
        }
        red[t] = mx;
        __syncthreads();
        for (int m = 32; m >= 1; m >>= 1) {
            if (t < m) { if (red[t + m] > red[t]) red[t] = red[t + m]; }
            __syncthreads();
        }
        mx = red[0];
        __syncthreads();
        float z = 0.0f;
        for (int p = t; p < cnt; p += 64) {
            float a = expf(esc[p] - mx);
            esc[p] = a;
            z += a;
        }
        red[t] = z;
        __syncthreads();
        for (int m = 32; m >= 1; m >>= 1) {
            if (t < m) red[t] += red[t + m];
            __syncthreads();
        }
        z = red[0];
        float rz = (cnt > 0) ? 1.0f / z : 0.0f;
        float rd = 0.0f;
        for (int p = 0; p < cnt; ++p) rd += x[(size_t)(n0 + p) * 64 + t] * esc[p];
        rd *= rz;
        __syncthreads();
        qs[t] = hh2[t];
        qs[64 + t] = rd;
        __syncthreads();
    }

    /* head: graphnorm -> fc1 -> bn -> relu -> fc2 -> relu */
    float q0 = qs[t];
    float q1 = qs[64 + t];
    red[t] = q0 + q1;
    __syncthreads();
    for (int m = 32; m >= 1; m >>= 1) {
        if (t < m) red[t] += red[t + m];
        __syncthreads();
    }
    float mu = red[0] * (1.0f / 128.0f);
    __syncthreads();
    red[t] = q0 * q0 + q1 * q1;
    __syncthreads();
    for (int m = 32; m >= 1; m >>= 1) {
        if (t < m) red[t] += red[t + m];
        __syncthreads();
    }
    float var = red[0] * (1.0f / 128.0f) - mu * mu;
    float rs = rsqrtf(var + 1e-5f);
    scr[t] = (q0 - mu) * rs * gn_g[t] + gn_b[t];
    scr[64 + t] = (q1 - mu) * rs * gn_g[64 + t] + gn_b[64 + t];
    __syncthreads();
    float y0 = fc1_b[t];
    float y1 = fc1_b[64 + t];
    for (int k = 0; k < 128; ++k) {
        float gv = scr[k];
        y0 += fc1_w[(size_t)t * 128 + k] * gv;
        y1 += fc1_w[(size_t)(64 + t) * 128 + k] * gv;
    }
    y0 = (y0 - bn_m[t]) * rsqrtf(bn_v[t] + 1e-5f) * bn_g[t] + bn_b[t];
    y1 = (y1 - bn_m[64 + t]) * rsqrtf(bn_v[64 + t] + 1e-5f) * bn_g[64 + t] + bn_b[64 + t];
    if (y0 < 0.0f) y0 = 0.0f;
    if (y1 < 0.0f) y1 = 0.0f;
    __syncthreads();
    scr[t] = y0;
    scr[64 + t] = y1;
    __syncthreads();
    float o = fc2_b[t];
    for (int k = 0; k < 128; ++k) o += fc2_w[(size_t)t * 128 + k] * scr[k];
    if (!(o == o)) o = 999.0f;          /* NaN canary (head) */
    else if (o < 0.0f) o = 0.0f;        /* final relu */
    out[(size_t)g * 64 + t] = o;
}

extern "C" void kernel_launch(void* const* d_in, const int* in_sizes, int n_in,
                              void* d_out, int out_size, void* d_ws, size_t ws_size,
                              hipStream_t stream) {
    float* out = (float*)d_out;                 /* reference output dtype is FLOAT32 */
    const int outBlocks = (KB * 64 + 255) / 256;

    if (n_in != 39) {
        GNNModule_9259949490279_kernel<<<outBlocks, 256, 0, stream>>>(out, 50.0f);
        return;
    }
    if (in_sizes[0] != KN * 64 || in_sizes[1] != KE || in_sizes[4] != KN) {
        GNNModule_9259949490279_kernel<<<outBlocks, 256, 0, stream>>>(out, 60.0f);
        return;
    }
    if (in_sizes[7] != 4096 * 32 || in_sizes[17] != 256 * 128 || in_sizes[37] != 64 * 128) {
        GNNModule_9259949490279_kernel<<<outBlocks, 256, 0, stream>>>(out, 70.0f);
        return;
    }
    if (out_size != KB * 64) {
        GNNModule_9259949490279_kernel<<<outBlocks, 256, 0, stream>>>(out, 80.0f);
        return;
    }
    if (ws_size < O_ZEND * 4) {
        GNNModule_9259949490279_kernel<<<outBlocks, 256, 0, stream>>>(out, 100.0f);
        return;
    }

    const float* atom = (const float*)d_in[0];
    const float* efeat = (const float*)d_in[1];
    const int* src = (const int*)d_in[2];
    const int* dst = (const int*)d_in[3];
    const int* gid = (const int*)d_in[4];
    const float* ew1_0 = (const float*)d_in[5];
    const float* eb1_0 = (const float*)d_in[6];
    const float* ew2_0 = (const float*)d_in[7];
    const float* eb2_0 = (const float*)d_in[8];
    const float* cb_0 = (const float*)d_in[9];
    const float* ew1_1 = (const float*)d_in[10];
    const float* eb1_1 = (const float*)d_in[11];
    const float* ew2_1 = (const float*)d_in[12];
    const float* eb2_1 = (const float*)d_in[13];
    const float* cb_1 = (const float*)d_in[14];
    const float* ln_g = (const float*)d_in[15];
    const float* ln_b = (const float*)d_in[16];
    const float* wih0 = (const float*)d_in[17];
    const float* whh0 = (const float*)d_in[18];
    const float* bih0 = (const float*)d_in[19];
    const float* bhh0 = (const float*)d_in[20];
    const float* wih1 = (const float*)d_in[21];
    const float* whh1 = (const float*)d_in[22];
    const float* bih1 = (const float*)d_in[23];
    const float* bhh1 = (const float*)d_in[24];
    const float* wih2 = (const float*)d_in[25];
    const float* whh2 = (const float*)d_in[26];
    const float* bih2 = (const float*)d_in[27];
    const float* bhh2 = (const float*)d_in[28];
    const float* gn_g = (const float*)d_in[29];
    const float* gn_b = (const float*)d_in[30];
    const float* fc1_w = (const float*)d_in[31];
    const float* fc1_b = (const float*)d_in[32];
    const float* bn_g = (const float*)d_in[33];
    const float* bn_b = (const float*)d_in[34];
    const float* bn_m = (const float*)d_in[35];
    const float* bn_v = (const float*)d_in[36];
    const float* fc2_w = (const float*)d_in[37];
    const float* fc2_b = (const float*)d_in[38];

    float* wsf = (float*)d_ws;
    int* wsi = (int*)d_ws;
    float* buf0 = wsf + O_BUF0;
    float* buf1 = wsf + O_BUF1;
    float* deg = wsf + O_DEG;
    int* gcnt = wsi + O_GCNT;
    int* gstart = wsi + O_GST;
    int* flag = wsi + O_FLAG;

    k_zero<<<2048, 256, 0, stream>>>(wsf);

    k_deg<<<KE / 256, 256, 0, stream>>>(dst, deg, flag);
    k_gcount<<<KN / 256, 256, 0, stream>>>(gid, gcnt, flag);
    k_gscan<<<1, 64, 0, stream>>>(gcnt, gstart);

    k_conv<<<KE / 64, 256, 0, stream>>>(atom, efeat, src, dst,
                                        ew1_0, eb1_0, ew2_0, eb2_0, buf0, flag);
    k_final0<<<KN * 64 / 256, 256, 0, stream>>>(buf0, deg, cb_0, flag);

    k_conv<<<KE / 64, 256, 0, stream>>>(buf0, efeat, src, dst,
                                        ew1_1, eb1_1, ew2_1, eb2_1, buf1, flag);
    k_final1ln<<<KN, 64, 0, stream>>>(buf1, deg, cb_1, ln_g, ln_b, flag);

    k_s2s<<<KB, 64, 0, stream>>>(buf1, gstart,
        wih0, whh0, bih0, bhh0,
        wih1, whh1, bih1, bhh1,
        wih2, whh2, bih2, bhh2,
        gn_g, gn_b, fc1_w, fc1_b, bn_g, bn_b, bn_m, bn_v, fc2_w, fc2_b,
        out, flag);

    k_post<<<outBlocks, 256, 0, stream>>>(flag, out);
}

// Round 9
// 2098.851 us; speedup vs baseline: 11.0449x; 11.0449x over previous
//
#include <hip/hip_runtime.h>

#define KN 32768
#define KE 65536
#define KB 512
#define KEPB 64
#define KNREG 33
#define KEORD (KE + KNREG * KEPB)   /* 67648 padded sorted-edge slots */
#define KNBLK (KEORD / KEPB)        /* 1057 edge blocks */

/* ---------------- workspace element offsets ---------------- */
/* zero-init zone */
#define O_BUF0 ((size_t)0)
#define O_BUF1 (O_BUF0 + (size_t)KN * 64)
#define O_DEG  (O_BUF1 + (size_t)KN * 64)
#define O_GCNT (O_DEG + KN)
#define O_GST  (O_GCNT + KB)
#define O_HIST (O_GST + KB + 8)          /* [2][64] */
#define O_CUR  (O_HIST + 128)            /* [2][64] */
#define O_FLAG (O_CUR + 128)
#define O_ZEND (O_FLAG + 64)
/* -1-init zone */
#define O_EORD ((O_ZEND + 63) & ~(size_t)63)    /* [2][KEORD] */
#define O_RBLK (O_EORD + 2 * (size_t)KEORD)     /* [2][1088] */
#define O_FEND (O_RBLK + 2 * 1088)
/* no-init zone (fully written before read) */
#define O_WB   ((O_FEND + 63) & ~(size_t)63)    /* [33][4096] */
#define O_WS   (O_WB + (size_t)KNREG * 4096)
#define O_CROSS (O_WS + (size_t)KNREG * 4096)   /* [32] */
#define O_RCNT (O_CROSS + 64)
#define O_AOFF (O_RCNT + 64)                     /* [2][64] */
#define O_REGN (O_AOFF + 128)                    /* [E] */
#define O_END  (O_REGN + KE)

__device__ float sigf(float x) { return 1.0f / (1.0f + expf(-x)); }

/* diagnostic fill (f32 output) */
extern "C" __global__ void GNNModule_9259949490279_kernel(float* out, float v) {
    int i = blockIdx.x * 256 + threadIdx.x;
    if (i < KB * 64) out[i] = v;
}

extern "C" __global__ void k_post(const int* flag, float* out) {
    int f = flag[0];
    if (f == 0) return;
    int i = blockIdx.x * 256 + threadIdx.x;
    if (i < KB * 64) out[i] = 300.0f + (float)f;
}

extern "C" __global__ void k_zero(float* ws) {
    size_t i = (size_t)blockIdx.x * 256 + threadIdx.x;
    size_t stride = (size_t)gridDim.x * 256;
    for (size_t p = i; p < O_ZEND; p += stride) ws[p] = 0.0f;
}

extern "C" __global__ void k_fillm1(int* ws) {
    size_t i = (size_t)blockIdx.x * 256 + threadIdx.x;
    size_t stride = (size_t)gridDim.x * 256;
    for (size_t p = O_EORD + i; p < O_FEND; p += stride) ws[p] = -1;
}

extern "C" __global__ void k_deg(const int* dst, float* deg, int* flag) {
    int e = blockIdx.x * 256 + threadIdx.x;
    if (e >= KE) return;
    int d = dst[e];
    if ((unsigned)d >= (unsigned)KN) { atomicOr(flag, 1); d = 0; }
    atomicAdd(&deg[d], 1.0f);
}

extern "C" __global__ void k_gcount(const int* gid, int* gcnt, int* flag) {
    int n = blockIdx.x * 256 + threadIdx.x;
    if (n >= KN) return;
    int g = gid[n];
    if ((unsigned)g >= (unsigned)KB) { atomicOr(flag, 2); g = 0; }
    atomicAdd(&gcnt[g], 1);
}

extern "C" __global__ void k_gscan(const int* gcnt, int* gstart) {
    __shared__ int part[64];
    __shared__ int pre[64];
    int t = threadIdx.x;
    int v[8];
    int s = 0;
    int base = t * 8;
    for (int j = 0; j < 8; ++j) { v[j] = gcnt[base + j]; s += v[j]; }
    part[t] = s;
    __syncthreads();
    if (t == 0) {
        int run = 0;
        for (int i = 0; i < 64; ++i) { pre[i] = run; run += part[i]; }
    }
    __syncthreads();
    int run = pre[t];
    for (int j = 0; j < 8; ++j) { gstart[base + j] = run; run += v[j]; }
    if (t == 63) gstart[KB] = run;
}

/* ---- region machinery: exact piecewise-linear edge MLP ----
   h_k(ef)=relu(ef*a_k+b_k) is linear between breakpoints t_k=-b_k/a_k.
   Within a region: W(ef)[idx] = Wb_r[idx] + ef*Ws_r[idx], EXACT. */
extern "C" __global__ void k_prep(const float* ew1, const float* eb1,
                                  float* cross, int* rcnt) {
    if (threadIdx.x != 0 || blockIdx.x != 0) return;
    float cl[32];
    int n = 0;
    for (int k = 0; k < 32; ++k) {
        float a = ew1[k], b = eb1[k];
        if (a != 0.0f) {
            float tt = -b / a;
            if (tt > 0.0f && tt < 1.0f) cl[n++] = tt;
        }
    }
    for (int i = 1; i < n; ++i) {
        float v = cl[i];
        int j = i - 1;
        while (j >= 0 && cl[j] > v) { cl[j + 1] = cl[j]; --j; }
        cl[j + 1] = v;
    }
    for (int i = 0; i < n; ++i) cross[i] = cl[i];
    *rcnt = n;
}

extern "C" __global__ __launch_bounds__(256) void k_mats(
    const float* ew1, const float* eb1, const float* ew2, const float* eb2,
    const float* cross, const int* rcnt, float* Wb, float* Ws) {
    int r = blockIdx.x;
    int n = *rcnt;
    if (r > n) return;
    float lo = (r == 0) ? 0.0f : cross[r - 1];
    float hi = (r == n) ? 1.0f : cross[r];
    float mid = 0.5f * (lo + hi);
    __shared__ float mw[32], mb[32];
    int t = threadIdx.x;
    if (t < 32) {
        bool act = (mid * ew1[t] + eb1[t]) > 0.0f;
        mw[t] = act ? ew1[t] : 0.0f;
        mb[t] = act ? eb1[t] : 0.0f;
    }
    __syncthreads();
    #pragma unroll
    for (int j = 0; j < 16; ++j) {
        int idx = j * 256 + t;
        float as = 0.0f, ab = eb2[idx];
        #pragma unroll
        for (int k4 = 0; k4 < 8; ++k4) {
            float4 w2 = *(const float4*)&ew2[(size_t)idx * 32 + 4 * k4];
            as += mw[4*k4+0]*w2.x + mw[4*k4+1]*w2.y + mw[4*k4+2]*w2.z + mw[4*k4+3]*w2.w;
            ab += mb[4*k4+0]*w2.x + mb[4*k4+1]*w2.y + mb[4*k4+2]*w2.z + mb[4*k4+3]*w2.w;
        }
        Wb[(size_t)r * 4096 + idx] = ab;
        Ws[(size_t)r * 4096 + idx] = as;
    }
}

extern "C" __global__ void k_region(const float* ef, const float* cross,
                                    const int* rcnt, int* region, int* hist) {
    int e = blockIdx.x * 256 + threadIdx.x;
    if (e >= KE) return;
    float f = ef[e];
    int n = *rcnt, r = 0;
    for (int j = 0; j < n; ++j) r += (f > cross[j]) ? 1 : 0;
    region[e] = r;
    atomicAdd(&hist[r], 1);
}

extern "C" __global__ void k_scan(const int* hist, const int* rcnt,
                                  int* aoff, int* rblk) {
    if (threadIdx.x != 0 || blockIdx.x != 0) return;
    int R = *rcnt + 1;
    int base = 0;
    for (int r = 0; r < R; ++r) {
        aoff[r] = base * KEPB;
        int nb = (hist[r] + KEPB - 1) / KEPB;
        for (int j = 0; j < nb; ++j) rblk[base + j] = r;
        base += nb;
    }
}

extern "C" __global__ void k_scatidx(const int* region, const int* aoff,
                                     int* cursor, int* eorder) {
    int e = blockIdx.x * 256 + threadIdx.x;
    if (e >= KE) return;
    int r = region[e];
    int pos = atomicAdd(&cursor[r], 1);
    eorder[aoff[r] + pos] = e;
}

/* ---- edge message + scatter: 64 same-region edges per block, 4 waves.
   Wave w owns 16 edges at lane=output dim o.
   m[e,o] = sum_i x[src_e,i]*(Wb[i*64+o] + ef_e*Ws[i*64+o]) */
extern "C" __global__ __launch_bounds__(256) void k_edge(
    const float* x, const float* efeat, const int* src, const int* dst,
    const float* Wb, const float* Ws, const int* rblk, const int* eorder,
    float* sbuf) {
    __shared__ __align__(16) float mbuf[4096];
    __shared__ __align__(16) float msuf[4096];
    __shared__ __align__(16) float xs[4][16][64];
    int b = blockIdx.x;
    int r = rblk[b];
    if (r < 0) return;
    int t = threadIdx.x;
    const float4* gb = (const float4*)(Wb + (size_t)r * 4096);
    const float4* gs = (const float4*)(Ws + (size_t)r * 4096);
    float4* lb = (float4*)mbuf;
    float4* ls = (float4*)msuf;
    #pragma unroll
    for (int j = 0; j < 4; ++j) {
        lb[t + 256 * j] = gb[t + 256 * j];
        ls[t + 256 * j] = gs[t + 256 * j];
    }
    __syncthreads();
    int w = t >> 6, lane = t & 63;
    int base = b * KEPB + w * 16;
    int eid = (lane < 16) ? eorder[base + lane] : -1;
    float efl = 0.0f;
    int srl = 0, dsl = 0;
    if (eid >= 0) { efl = efeat[eid]; srl = src[eid]; dsl = dst[eid]; }
    unsigned long long vm = __ballot(eid >= 0);
    if ((vm & 0xFFFFull) == 0ull) return;
    float ef[16];
    int dv[16];
    #pragma unroll
    for (int s = 0; s < 16; ++s) {
        ef[s] = __shfl(efl, s);
        int sv = __shfl(srl, s);
        dv[s] = __shfl(dsl, s);
        xs[w][s][lane] = x[(size_t)sv * 64 + lane];
    }
    float acc[16];
    #pragma unroll
    for (int s = 0; s < 16; ++s) acc[s] = 0.0f;
    #pragma unroll 1
    for (int i4 = 0; i4 < 16; ++i4) {
        float wb0 = mbuf[(i4 * 4 + 0) * 64 + lane], ws0 = msuf[(i4 * 4 + 0) * 64 + lane];
        float wb1 = mbuf[(i4 * 4 + 1) * 64 + lane], ws1 = msuf[(i4 * 4 + 1) * 64 + lane];
        float wb2 = mbuf[(i4 * 4 + 2) * 64 + lane], ws2 = msuf[(i4 * 4 + 2) * 64 + lane];
        float wb3 = mbuf[(i4 * 4 + 3) * 64 + lane], ws3 = msuf[(i4 * 4 + 3) * 64 + lane];
        #pragma unroll
        for (int j = 0; j < 16; ++j) {
            float4 xv = *(const float4*)&xs[w][j][i4 * 4];
            acc[j] = fmaf(xv.x, fmaf(ef[j], ws0, wb0), acc[j]);
            acc[j] = fmaf(xv.y, fmaf(ef[j], ws1, wb1), acc[j]);
            acc[j] = fmaf(xv.z, fmaf(ef[j], ws2, wb2), acc[j]);
            acc[j] = fmaf(xv.w, fmaf(ef[j], ws3, wb3), acc[j]);
        }
    }
    #pragma unroll
    for (int j = 0; j < 16; ++j) {
        if ((vm >> j) & 1ull) atomicAdd(&sbuf[(size_t)dv[j] * 64 + lane], acc[j]);
    }
}

extern "C" __global__ void k_final0(float* s, const float* deg, const float* cb, int* flag) {
    int idx = blockIdx.x * 256 + threadIdx.x;
    int n = idx >> 6;
    int o = idx & 63;
    float d = deg[n];
    if (d < 1.0f) d = 1.0f;
    float v = s[idx] / d + cb[o];
    if (v < 0.0f) v = 0.0f;
    if (!(v == v)) { v = 0.0f; atomicOr(flag, 32); }
    s[idx] = v;
}

extern "C" __global__ void k_final1ln(float* s, const float* deg, const float* cb,
                                      const float* lg, const float* lb, int* flag) {
    __shared__ float red[64];
    int t = threadIdx.x;
    int n = blockIdx.x;
    float d = deg[n];
    if (d < 1.0f) d = 1.0f;
    float v = s[(size_t)n * 64 + t] / d + cb[t];
    if (v < 0.0f) v = 0.0f;
    red[t] = v;
    __syncthreads();
    for (int m = 32; m >= 1; m >>= 1) {
        if (t < m) red[t] += red[t + m];
        __syncthreads();
    }
    float mu = red[0] * (1.0f / 64.0f);
    __syncthreads();
    red[t] = v * v;
    __syncthreads();
    for (int m = 32; m >= 1; m >>= 1) {
        if (t < m) red[t] += red[t + m];
        __syncthreads();
    }
    float var = red[0] * (1.0f / 64.0f) - mu * mu;
    float rs = rsqrtf(var + 1e-5f);
    float r = (v - mu) * rs * lg[t] + lb[t];
    if (!(r == r)) { r = 0.0f; atomicOr(flag, 8); }
    s[(size_t)n * 64 + t] = r;
}

/* one graph per block, 64 threads — HW-verified in round 8, kept verbatim */
extern "C" __global__ void k_s2s(
    const float* x, const int* gstart,
    const float* wih0, const float* whh0, const float* bih0, const float* bhh0,
    const float* wih1, const float* whh1, const float* bih1, const float* bhh1,
    const float* wih2, const float* whh2, const float* bih2, const float* bhh2,
    const float* gn_g, const float* gn_b,
    const float* fc1_w, const float* fc1_b,
    const float* bn_g, const float* bn_b, const float* bn_m, const float* bn_v,
    const float* fc2_w, const float* fc2_b,
    float* out, int* flag) {
    __shared__ float qs[128];
    __shared__ float hh0[64];
    __shared__ float hh1[64];
    __shared__ float hh2[64];
    __shared__ float esc[1024];
    __shared__ float red[64];
    __shared__ float scr[128];
    int t = threadIdx.x;
    int g = blockIdx.x;

    qs[t] = 0.0f;
    qs[64 + t] = 0.0f;
    hh0[t] = 0.0f;
    hh1[t] = 0.0f;
    hh2[t] = 0.0f;
    float c0 = 0.0f, c1 = 0.0f, c2 = 0.0f;
    __syncthreads();

    int n0 = gstart[g];
    int n1 = gstart[g + 1];
    if (n0 < 0) n0 = 0;
    if (n0 > KN) n0 = KN;
    if (n1 < n0) n1 = n0;
    if (n1 > KN) n1 = KN;
    int cnt = n1 - n0;
    if (cnt > 1024) { cnt = 1024; if (t == 0) atomicOr(flag, 16); }

    for (int it = 0; it < 6; ++it) {
        {
            float gi = bih0[t] + bhh0[t];
            float gf = bih0[64 + t] + bhh0[64 + t];
            float gg = bih0[128 + t] + bhh0[128 + t];
            float go = bih0[192 + t] + bhh0[192 + t];
            for (int k = 0; k < 128; ++k) {
                float v = qs[k];
                gi += wih0[(size_t)t * 128 + k] * v;
                gf += wih0[(size_t)(64 + t) * 128 + k] * v;
                gg += wih0[(size_t)(128 + t) * 128 + k] * v;
                go += wih0[(size_t)(192 + t) * 128 + k] * v;
            }
            for (int k = 0; k < 64; ++k) {
                float v = hh0[k];
                gi += whh0[(size_t)t * 64 + k] * v;
                gf += whh0[(size_t)(64 + t) * 64 + k] * v;
                gg += whh0[(size_t)(128 + t) * 64 + k] * v;
                go += whh0[(size_t)(192 + t) * 64 + k] * v;
            }
            c0 = sigf(gf) * c0 + sigf(gi) * tanhf(gg);
            float hn = sigf(go) * tanhf(c0);
            __syncthreads();
            hh0[t] = hn;
            __syncthreads();
        }
        {
            float gi = bih1[t] + bhh1[t];
            float gf = bih1[64 + t] + bhh1[64 + t];
            float gg = bih1[128 + t] + bhh1[128 + t];
            float go = bih1[192 + t] + bhh1[192 + t];
            for (int k = 0; k < 64; ++k) {
                float v = hh0[k];
                gi += wih1[(size_t)t * 64 + k] * v;
                gf += wih1[(size_t)(64 + t) * 64 + k] * v;
                gg += wih1[(size_t)(128 + t) * 64 + k] * v;
                go += wih1[(size_t)(192 + t) * 64 + k] * v;
            }
            for (int k = 0; k < 64; ++k) {
                float v = hh1[k];
                gi += whh1[(size_t)t * 64 + k] * v;
                gf += whh1[(size_t)(64 + t) * 64 + k] * v;
                gg += whh1[(size_t)(128 + t) * 64 + k] * v;
                go += whh1[(size_t)(192 + t) * 64 + k] * v;
            }
            c1 = sigf(gf) * c1 + sigf(gi) * tanhf(gg);
            float hn = sigf(go) * tanhf(c1);
            __syncthreads();
            hh1[t] = hn;
            __syncthreads();
        }
        {
            float gi = bih2[t] + bhh2[t];
            float gf = bih2[64 + t] + bhh2[64 + t];
            float gg = bih2[128 + t] + bhh2[128 + t];
            float go = bih2[192 + t] + bhh2[192 + t];
            for (int k = 0; k < 64; ++k) {
                float v = hh1[k];
                gi += wih2[(size_t)t * 64 + k] * v;
                gf += wih2[(size_t)(64 + t) * 64 + k] * v;
                gg += wih2[(size_t)(128 + t) * 64 + k] * v;
                go += wih2[(size_t)(192 + t) * 64 + k] * v;
            }
            for (int k = 0; k < 64; ++k) {
                float v = hh2[k];
                gi += whh2[(size_t)t * 64 + k] * v;
                gf += whh2[(size_t)(64 + t) * 64 + k] * v;
                gg += whh2[(size_t)(128 + t) * 64 + k] * v;
                go += whh2[(size_t)(192 + t) * 64 + k] * v;
            }
            c2 = sigf(gf) * c2 + sigf(gi) * tanhf(gg);
            float hn = sigf(go) * tanhf(c2);
            __syncthreads();
            hh2[t] = hn;
            __syncthreads();
        }
        float mx = -1e30f;
        for (int p = t; p < cnt; p += 64) {
            size_t bb = (size_t)(n0 + p) * 64;
            float a = 0.0f;
            for (int k = 0; k < 64; ++k) a += x[bb + k] * hh2[k];
            esc[p] = a;
            if (a > mx) mx = a;
        }
        red[t] = mx;
        __syncthreads();
        for (int m = 32; m >= 1; m >>= 1) {
            if (t < m) { if (red[t + m] > red[t]) red[t] = red[t + m]; }
            __syncthreads();
        }
        mx = red[0];
        __syncthreads();
        float z = 0.0f;
        for (int p = t; p < cnt; p += 64) {
            float a = expf(esc[p] - mx);
            esc[p] = a;
            z += a;
        }
        red[t] = z;
        __syncthreads();
        for (int m = 32; m >= 1; m >>= 1) {
            if (t < m) red[t] += red[t + m];
            __syncthreads();
        }
        z = red[0];
        float rz = (cnt > 0) ? 1.0f / z : 0.0f;
        float rd = 0.0f;
        for (int p = 0; p < cnt; ++p) rd += x[(size_t)(n0 + p) * 64 + t] * esc[p];
        rd *= rz;
        __syncthreads();
        qs[t] = hh2[t];
        qs[64 + t] = rd;
        __syncthreads();
    }

    float q0 = qs[t];
    float q1 = qs[64 + t];
    red[t] = q0 + q1;
    __syncthreads();
    for (int m = 32; m >= 1; m >>= 1) {
        if (t < m) red[t] += red[t + m];
        __syncthreads();
    }
    float mu = red[0] * (1.0f / 128.0f);
    __syncthreads();
    red[t] = q0 * q0 + q1 * q1;
    __syncthreads();
    for (int m = 32; m >= 1; m >>= 1) {
        if (t < m) red[t] += red[t + m];
        __syncthreads();
    }
    float var = red[0] * (1.0f / 128.0f) - mu * mu;
    float rs = rsqrtf(var + 1e-5f);
    scr[t] = (q0 - mu) * rs * gn_g[t] + gn_b[t];
    scr[64 + t] = (q1 - mu) * rs * gn_g[64 + t] + gn_b[64 + t];
    __syncthreads();
    float y0 = fc1_b[t];
    float y1 = fc1_b[64 + t];
    for (int k = 0; k < 128; ++k) {
        float gv = scr[k];
        y0 += fc1_w[(size_t)t * 128 + k] * gv;
        y1 += fc1_w[(size_t)(64 + t) * 128 + k] * gv;
    }
    y0 = (y0 - bn_m[t]) * rsqrtf(bn_v[t] + 1e-5f) * bn_g[t] + bn_b[t];
    y1 = (y1 - bn_m[64 + t]) * rsqrtf(bn_v[64 + t] + 1e-5f) * bn_g[64 + t] + bn_b[64 + t];
    if (y0 < 0.0f) y0 = 0.0f;
    if (y1 < 0.0f) y1 = 0.0f;
    __syncthreads();
    scr[t] = y0;
    scr[64 + t] = y1;
    __syncthreads();
    float o = fc2_b[t];
    for (int k = 0; k < 128; ++k) o += fc2_w[(size_t)t * 128 + k] * scr[k];
    if (!(o == o)) o = 999.0f;
    else if (o < 0.0f) o = 0.0f;
    out[(size_t)g * 64 + t] = o;
}

extern "C" void kernel_launch(void* const* d_in, const int* in_sizes, int n_in,
                              void* d_out, int out_size, void* d_ws, size_t ws_size,
                              hipStream_t stream) {
    float* out = (float*)d_out;
    const int outBlocks = (KB * 64 + 255) / 256;

    if (n_in != 39) {
        GNNModule_9259949490279_kernel<<<outBlocks, 256, 0, stream>>>(out, 50.0f);
        return;
    }
    if (in_sizes[0] != KN * 64 || in_sizes[1] != KE || in_sizes[4] != KN) {
        GNNModule_9259949490279_kernel<<<outBlocks, 256, 0, stream>>>(out, 60.0f);
        return;
    }
    if (out_size != KB * 64) {
        GNNModule_9259949490279_kernel<<<outBlocks, 256, 0, stream>>>(out, 80.0f);
        return;
    }
    if (ws_size < O_END * 4) {
        GNNModule_9259949490279_kernel<<<outBlocks, 256, 0, stream>>>(out, 100.0f);
        return;
    }

    const float* atom = (const float*)d_in[0];
    const float* efeat = (const float*)d_in[1];
    const int* src = (const int*)d_in[2];
    const int* dst = (const int*)d_in[3];
    const int* gid = (const int*)d_in[4];
    const float* ew1[2] = {(const float*)d_in[5], (const float*)d_in[10]};
    const float* eb1[2] = {(const float*)d_in[6], (const float*)d_in[11]};
    const float* ew2[2] = {(const float*)d_in[7], (const float*)d_in[12]};
    const float* eb2[2] = {(const float*)d_in[8], (const float*)d_in[13]};
    const float* cb[2] = {(const float*)d_in[9], (const float*)d_in[14]};
    const float* ln_g = (const float*)d_in[15];
    const float* ln_b = (const float*)d_in[16];
    const float* wih0 = (const float*)d_in[17];
    const float* whh0 = (const float*)d_in[18];
    const float* bih0 = (const float*)d_in[19];
    const float* bhh0 = (const float*)d_in[20];
    const float* wih1 = (const float*)d_in[21];
    const float* whh1 = (const float*)d_in[22];
    const float* bih1 = (const float*)d_in[23];
    const float* bhh1 = (const float*)d_in[24];
    const float* wih2 = (const float*)d_in[25];
    const float* whh2 = (const float*)d_in[26];
    const float* bih2 = (const float*)d_in[27];
    const float* bhh2 = (const float*)d_in[28];
    const float* gn_g = (const float*)d_in[29];
    const float* gn_b = (const float*)d_in[30];
    const float* fc1_w = (const float*)d_in[31];
    const float* fc1_b = (const float*)d_in[32];
    const float* bn_g = (const float*)d_in[33];
    const float* bn_b = (const float*)d_in[34];
    const float* bn_m = (const float*)d_in[35];
    const float* bn_v = (const float*)d_in[36];
    const float* fc2_w = (const float*)d_in[37];
    const float* fc2_b = (const float*)d_in[38];

    float* wsf = (float*)d_ws;
    int* wsi = (int*)d_ws;
    float* buf0 = wsf + O_BUF0;
    float* buf1 = wsf + O_BUF1;
    float* deg = wsf + O_DEG;
    int* gcnt = wsi + O_GCNT;
    int* gstart = wsi + O_GST;
    int* flag = wsi + O_FLAG;
    float* Wb = wsf + O_WB;
    float* Ws = wsf + O_WS;
    float* cross = wsf + O_CROSS;
    int* rcnt = wsi + O_RCNT;
    int* region = wsi + O_REGN;

    k_zero<<<2048, 256, 0, stream>>>(wsf);
    k_fillm1<<<256, 256, 0, stream>>>(wsi);

    k_deg<<<KE / 256, 256, 0, stream>>>(dst, deg, flag);
    k_gcount<<<KN / 256, 256, 0, stream>>>(gid, gcnt, flag);
    k_gscan<<<1, 64, 0, stream>>>(gcnt, gstart);

    for (int l = 0; l < 2; ++l) {
        const float* xin = (l == 0) ? atom : buf0;
        float* sout = (l == 0) ? buf0 : buf1;
        int* hist = wsi + O_HIST + l * 64;
        int* cursor = wsi + O_CUR + l * 64;
        int* aoff = wsi + O_AOFF + l * 64;
        int* eorder = wsi + O_EORD + l * KEORD;
        int* rblk = wsi + O_RBLK + l * 1088;

        k_prep<<<1, 64, 0, stream>>>(ew1[l], eb1[l], cross, rcnt);
        k_mats<<<KNREG, 256, 0, stream>>>(ew1[l], eb1[l], ew2[l], eb2[l], cross, rcnt, Wb, Ws);
        k_region<<<KE / 256, 256, 0, stream>>>(efeat, cross, rcnt, region, hist);
        k_scan<<<1, 64, 0, stream>>>(hist, rcnt, aoff, rblk);
        k_scatidx<<<KE / 256, 256, 0, stream>>>(region, aoff, cursor, eorder);
        k_edge<<<KNBLK, 256, 0, stream>>>(xin, efeat, src, dst, Wb, Ws, rblk, eorder, sout);
        if (l == 0) {
            k_final0<<<KN * 64 / 256, 256, 0, stream>>>(buf0, deg, cb[0], flag);
        } else {
            k_final1ln<<<KN, 64, 0, stream>>>(buf1, deg, cb[1], ln_g, ln_b, flag);
        }
    }

    k_s2s<<<KB, 64, 0, stream>>>(buf1, gstart,
        wih0, whh0, bih0, bhh0,
        wih1, whh1, bih1, bhh1,
        wih2, whh2, bih2, bhh2,
        gn_g, gn_b, fc1_w, fc1_b, bn_g, bn_b, bn_m, bn_v, fc2_w, fc2_b,
        out, flag);

    k_post<<<outBlocks, 256, 0, stream>>>(flag, out);
}

// Round 10
// 1763.577 us; speedup vs baseline: 13.1447x; 1.1901x over previous
//
#include <hip/hip_runtime.h>

#define KN 32768
#define KE 65536
#define KB 512
#define KEPB 64
#define KNREG 33
#define KEORD (KE + KNREG * KEPB)   /* 67648 padded sorted-edge slots */
#define KNBLK (KEORD / KEPB)        /* 1057 edge blocks */

/* ---------------- workspace element offsets ---------------- */
/* zero-init zone */
#define O_BUF0 ((size_t)0)
#define O_BUF1 (O_BUF0 + (size_t)KN * 64)
#define O_DEG  (O_BUF1 + (size_t)KN * 64)
#define O_GCNT (O_DEG + KN)
#define O_GST  (O_GCNT + KB)
#define O_HIST (O_GST + KB + 8)          /* [2][64] */
#define O_CUR  (O_HIST + 128)            /* [2][64] */
#define O_FLAG (O_CUR + 128)
#define O_ZEND (O_FLAG + 64)
/* -1-init zone */
#define O_EORD ((O_ZEND + 63) & ~(size_t)63)    /* [2][KEORD] */
#define O_RBLK (O_EORD + 2 * (size_t)KEORD)     /* [2][1088] */
#define O_FEND (O_RBLK + 2 * 1088)
/* no-init zone (fully written before read) */
#define O_WB   ((O_FEND + 63) & ~(size_t)63)    /* [33][4096] */
#define O_WS   (O_WB + (size_t)KNREG * 4096)
#define O_CROSS (O_WS + (size_t)KNREG * 4096)   /* [32] */
#define O_RCNT (O_CROSS + 64)
#define O_AOFF (O_RCNT + 64)                     /* [2][64] */
#define O_REGN (O_AOFF + 128)                    /* [E] */
#define O_END  (O_REGN + KE)

__device__ float sigf(float x) { return 1.0f / (1.0f + expf(-x)); }

/* diagnostic fill (f32 output) */
extern "C" __global__ void GNNModule_9259949490279_kernel(float* out, float v) {
    int i = blockIdx.x * 256 + threadIdx.x;
    if (i < KB * 64) out[i] = v;
}

extern "C" __global__ void k_post(const int* flag, float* out) {
    int f = flag[0];
    if (f == 0) return;
    int i = blockIdx.x * 256 + threadIdx.x;
    if (i < KB * 64) out[i] = 300.0f + (float)f;
}

extern "C" __global__ void k_zero(float* ws) {
    size_t i = (size_t)blockIdx.x * 256 + threadIdx.x;
    size_t stride = (size_t)gridDim.x * 256;
    for (size_t p = i; p < O_ZEND; p += stride) ws[p] = 0.0f;
}

extern "C" __global__ void k_fillm1(int* ws) {
    size_t i = (size_t)blockIdx.x * 256 + threadIdx.x;
    size_t stride = (size_t)gridDim.x * 256;
    for (size_t p = O_EORD + i; p < O_FEND; p += stride) ws[p] = -1;
}

extern "C" __global__ void k_deg(const int* dst, float* deg, int* flag) {
    int e = blockIdx.x * 256 + threadIdx.x;
    if (e >= KE) return;
    int d = dst[e];
    if ((unsigned)d >= (unsigned)KN) { atomicOr(flag, 1); d = 0; }
    atomicAdd(&deg[d], 1.0f);
}

extern "C" __global__ void k_gcount(const int* gid, int* gcnt, int* flag) {
    int n = blockIdx.x * 256 + threadIdx.x;
    if (n >= KN) return;
    int g = gid[n];
    if ((unsigned)g >= (unsigned)KB) { atomicOr(flag, 2); g = 0; }
    atomicAdd(&gcnt[g], 1);
}

extern "C" __global__ void k_gscan(const int* gcnt, int* gstart) {
    __shared__ int part[64];
    __shared__ int pre[64];
    int t = threadIdx.x;
    int v[8];
    int s = 0;
    int base = t * 8;
    for (int j = 0; j < 8; ++j) { v[j] = gcnt[base + j]; s += v[j]; }
    part[t] = s;
    __syncthreads();
    if (t == 0) {
        int run = 0;
        for (int i = 0; i < 64; ++i) { pre[i] = run; run += part[i]; }
    }
    __syncthreads();
    int run = pre[t];
    for (int j = 0; j < 8; ++j) { gstart[base + j] = run; run += v[j]; }
    if (t == 63) gstart[KB] = run;
}

/* ---- region machinery: exact piecewise-linear edge MLP ---- */
extern "C" __global__ void k_prep(const float* ew1, const float* eb1,
                                  float* cross, int* rcnt) {
    if (threadIdx.x != 0 || blockIdx.x != 0) return;
    float cl[32];
    int n = 0;
    for (int k = 0; k < 32; ++k) {
        float a = ew1[k], b = eb1[k];
        if (a != 0.0f) {
            float tt = -b / a;
            if (tt > 0.0f && tt < 1.0f) cl[n++] = tt;
        }
    }
    for (int i = 1; i < n; ++i) {
        float v = cl[i];
        int j = i - 1;
        while (j >= 0 && cl[j] > v) { cl[j + 1] = cl[j]; --j; }
        cl[j + 1] = v;
    }
    for (int i = 0; i < n; ++i) cross[i] = cl[i];
    *rcnt = n;
}

extern "C" __global__ __launch_bounds__(256) void k_mats(
    const float* ew1, const float* eb1, const float* ew2, const float* eb2,
    const float* cross, const int* rcnt, float* Wb, float* Ws) {
    int r = blockIdx.x;
    int n = *rcnt;
    if (r > n) return;
    float lo = (r == 0) ? 0.0f : cross[r - 1];
    float hi = (r == n) ? 1.0f : cross[r];
    float mid = 0.5f * (lo + hi);
    __shared__ float mw[32], mb[32];
    int t = threadIdx.x;
    if (t < 32) {
        bool act = (mid * ew1[t] + eb1[t]) > 0.0f;
        mw[t] = act ? ew1[t] : 0.0f;
        mb[t] = act ? eb1[t] : 0.0f;
    }
    __syncthreads();
    #pragma unroll
    for (int j = 0; j < 16; ++j) {
        int idx = j * 256 + t;
        float as = 0.0f, ab = eb2[idx];
        #pragma unroll
        for (int k4 = 0; k4 < 8; ++k4) {
            float4 w2 = *(const float4*)&ew2[(size_t)idx * 32 + 4 * k4];
            as += mw[4*k4+0]*w2.x + mw[4*k4+1]*w2.y + mw[4*k4+2]*w2.z + mw[4*k4+3]*w2.w;
            ab += mb[4*k4+0]*w2.x + mb[4*k4+1]*w2.y + mb[4*k4+2]*w2.z + mb[4*k4+3]*w2.w;
        }
        Wb[(size_t)r * 4096 + idx] = ab;
        Ws[(size_t)r * 4096 + idx] = as;
    }
}

extern "C" __global__ void k_region(const float* ef, const float* cross,
                                    const int* rcnt, int* region, int* hist) {
    int e = blockIdx.x * 256 + threadIdx.x;
    if (e >= KE) return;
    float f = ef[e];
    int n = *rcnt, r = 0;
    for (int j = 0; j < n; ++j) r += (f > cross[j]) ? 1 : 0;
    region[e] = r;
    atomicAdd(&hist[r], 1);
}

extern "C" __global__ void k_scan(const int* hist, const int* rcnt,
                                  int* aoff, int* rblk) {
    if (threadIdx.x != 0 || blockIdx.x != 0) return;
    int R = *rcnt + 1;
    int base = 0;
    for (int r = 0; r < R; ++r) {
        aoff[r] = base * KEPB;
        int nb = (hist[r] + KEPB - 1) / KEPB;
        for (int j = 0; j < nb; ++j) rblk[base + j] = r;
        base += nb;
    }
}

extern "C" __global__ void k_scatidx(const int* region, const int* aoff,
                                     int* cursor, int* eorder) {
    int e = blockIdx.x * 256 + threadIdx.x;
    if (e >= KE) return;
    int r = region[e];
    int pos = atomicAdd(&cursor[r], 1);
    eorder[aoff[r] + pos] = e;
}

/* ---- edge message + scatter (HW-verified round 9, kept verbatim) ---- */
extern "C" __global__ __launch_bounds__(256) void k_edge(
    const float* x, const float* efeat, const int* src, const int* dst,
    const float* Wb, const float* Ws, const int* rblk, const int* eorder,
    float* sbuf) {
    __shared__ __align__(16) float mbuf[4096];
    __shared__ __align__(16) float msuf[4096];
    __shared__ __align__(16) float xs[4][16][64];
    int b = blockIdx.x;
    int r = rblk[b];
    if (r < 0) return;
    int t = threadIdx.x;
    const float4* gb = (const float4*)(Wb + (size_t)r * 4096);
    const float4* gs = (const float4*)(Ws + (size_t)r * 4096);
    float4* lb = (float4*)mbuf;
    float4* ls = (float4*)msuf;
    #pragma unroll
    for (int j = 0; j < 4; ++j) {
        lb[t + 256 * j] = gb[t + 256 * j];
        ls[t + 256 * j] = gs[t + 256 * j];
    }
    __syncthreads();
    int w = t >> 6, lane = t & 63;
    int base = b * KEPB + w * 16;
    int eid = (lane < 16) ? eorder[base + lane] : -1;
    float efl = 0.0f;
    int srl = 0, dsl = 0;
    if (eid >= 0) { efl = efeat[eid]; srl = src[eid]; dsl = dst[eid]; }
    unsigned long long vm = __ballot(eid >= 0);
    if ((vm & 0xFFFFull) == 0ull) return;
    float ef[16];
    int dv[16];
    #pragma unroll
    for (int s = 0; s < 16; ++s) {
        ef[s] = __shfl(efl, s);
        int sv = __shfl(srl, s);
        dv[s] = __shfl(dsl, s);
        xs[w][s][lane] = x[(size_t)sv * 64 + lane];
    }
    float acc[16];
    #pragma unroll
    for (int s = 0; s < 16; ++s) acc[s] = 0.0f;
    #pragma unroll 1
    for (int i4 = 0; i4 < 16; ++i4) {
        float wb0 = mbuf[(i4 * 4 + 0) * 64 + lane], ws0 = msuf[(i4 * 4 + 0) * 64 + lane];
        float wb1 = mbuf[(i4 * 4 + 1) * 64 + lane], ws1 = msuf[(i4 * 4 + 1) * 64 + lane];
        float wb2 = mbuf[(i4 * 4 + 2) * 64 + lane], ws2 = msuf[(i4 * 4 + 2) * 64 + lane];
        float wb3 = mbuf[(i4 * 4 + 3) * 64 + lane], ws3 = msuf[(i4 * 4 + 3) * 64 + lane];
        #pragma unroll
        for (int j = 0; j < 16; ++j) {
            float4 xv = *(const float4*)&xs[w][j][i4 * 4];
            acc[j] = fmaf(xv.x, fmaf(ef[j], ws0, wb0), acc[j]);
            acc[j] = fmaf(xv.y, fmaf(ef[j], ws1, wb1), acc[j]);
            acc[j] = fmaf(xv.z, fmaf(ef[j], ws2, wb2), acc[j]);
            acc[j] = fmaf(xv.w, fmaf(ef[j], ws3, wb3), acc[j]);
        }
    }
    #pragma unroll
    for (int j = 0; j < 16; ++j) {
        if ((vm >> j) & 1ull) atomicAdd(&sbuf[(size_t)dv[j] * 64 + lane], acc[j]);
    }
}

extern "C" __global__ void k_final0(float* s, const float* deg, const float* cb, int* flag) {
    int idx = blockIdx.x * 256 + threadIdx.x;
    int n = idx >> 6;
    int o = idx & 63;
    float d = deg[n];
    if (d < 1.0f) d = 1.0f;
    float v = s[idx] / d + cb[o];
    if (v < 0.0f) v = 0.0f;
    if (!(v == v)) { v = 0.0f; atomicOr(flag, 32); }
    s[idx] = v;
}

extern "C" __global__ void k_final1ln(float* s, const float* deg, const float* cb,
                                      const float* lg, const float* lb, int* flag) {
    __shared__ float red[64];
    int t = threadIdx.x;
    int n = blockIdx.x;
    float d = deg[n];
    if (d < 1.0f) d = 1.0f;
    float v = s[(size_t)n * 64 + t] / d + cb[t];
    if (v < 0.0f) v = 0.0f;
    red[t] = v;
    __syncthreads();
    for (int m = 32; m >= 1; m >>= 1) {
        if (t < m) red[t] += red[t + m];
        __syncthreads();
    }
    float mu = red[0] * (1.0f / 64.0f);
    __syncthreads();
    red[t] = v * v;
    __syncthreads();
    for (int m = 32; m >= 1; m >>= 1) {
        if (t < m) red[t] += red[t + m];
        __syncthreads();
    }
    float var = red[0] * (1.0f / 64.0f) - mu * mu;
    float rs = rsqrtf(var + 1e-5f);
    float r = (v - mu) * rs * lg[t] + lb[t];
    if (!(r == r)) { r = 0.0f; atomicOr(flag, 8); }
    s[(size_t)n * 64 + t] = r;
}

/* ---- Set2Set + head, 256 threads/block: thread gt owns gate row gt;
   float4 weight rows; 4-wave attention; parallel head ---- */
extern "C" __global__ __launch_bounds__(256) void k_s2s(
    const float* x, const int* gstart,
    const float* wih0, const float* whh0, const float* bih0, const float* bhh0,
    const float* wih1, const float* whh1, const float* bih1, const float* bhh1,
    const float* wih2, const float* whh2, const float* bih2, const float* bhh2,
    const float* gn_g, const float* gn_b,
    const float* fc1_w, const float* fc1_b,
    const float* bn_g, const float* bn_b, const float* bn_m, const float* bn_v,
    const float* fc2_w, const float* fc2_b,
    float* out, int* flag) {
    __shared__ __align__(16) float qs[128];
    __shared__ __align__(16) float hs0[64];
    __shared__ __align__(16) float hs1[64];
    __shared__ __align__(16) float hs2[64];
    __shared__ __align__(16) float cs[3][64];
    __shared__ __align__(16) float gat[256];
    __shared__ __align__(16) float esc[1024];
    __shared__ __align__(16) float red4[4][64];
    __shared__ __align__(16) float scr[128];
    int t = threadIdx.x;           /* 0..255 */
    int g = blockIdx.x;
    int w = t >> 6, lane = t & 63;

    if (t < 128) qs[t] = 0.0f;
    if (t < 64) {
        hs0[t] = 0.0f; hs1[t] = 0.0f; hs2[t] = 0.0f;
        cs[0][t] = 0.0f; cs[1][t] = 0.0f; cs[2][t] = 0.0f;
    }
    __syncthreads();

    int n0 = gstart[g];
    int n1 = gstart[g + 1];
    if (n0 < 0) n0 = 0;
    if (n0 > KN) n0 = KN;
    if (n1 < n0) n1 = n0;
    if (n1 > KN) n1 = KN;
    int cnt = n1 - n0;
    if (cnt > 1024) { cnt = 1024; if (t == 0) atomicOr(flag, 16); }

    for (int it = 0; it < 6; ++it) {
        /* layer 0: K=128, input qs */
        {
            float a = bih0[t] + bhh0[t];
            const float4* wr = (const float4*)(wih0 + (size_t)t * 128);
            #pragma unroll
            for (int k4 = 0; k4 < 32; ++k4) {
                float4 wv = wr[k4];
                float4 xv = *(const float4*)&qs[4 * k4];
                a += wv.x*xv.x + wv.y*xv.y + wv.z*xv.z + wv.w*xv.w;
            }
            const float4* ur = (const float4*)(whh0 + (size_t)t * 64);
            #pragma unroll
            for (int k4 = 0; k4 < 16; ++k4) {
                float4 wv = ur[k4];
                float4 hv = *(const float4*)&hs0[4 * k4];
                a += wv.x*hv.x + wv.y*hv.y + wv.z*hv.z + wv.w*hv.w;
            }
            gat[t] = a;
            __syncthreads();
            if (t < 64) {
                float c = sigf(gat[64 + t]) * cs[0][t] + sigf(gat[t]) * tanhf(gat[128 + t]);
                cs[0][t] = c;
                hs0[t] = sigf(gat[192 + t]) * tanhf(c);
            }
            __syncthreads();
        }
        /* layer 1: K=64, input hs0 */
        {
            float a = bih1[t] + bhh1[t];
            const float4* wr = (const float4*)(wih1 + (size_t)t * 64);
            const float4* ur = (const float4*)(whh1 + (size_t)t * 64);
            #pragma unroll
            for (int k4 = 0; k4 < 16; ++k4) {
                float4 wv = wr[k4];
                float4 xv = *(const float4*)&hs0[4 * k4];
                a += wv.x*xv.x + wv.y*xv.y + wv.z*xv.z + wv.w*xv.w;
                float4 uv = ur[k4];
                float4 hv = *(const float4*)&hs1[4 * k4];
                a += uv.x*hv.x + uv.y*hv.y + uv.z*hv.z + uv.w*hv.w;
            }
            gat[t] = a;
            __syncthreads();
            if (t < 64) {
                float c = sigf(gat[64 + t]) * cs[1][t] + sigf(gat[t]) * tanhf(gat[128 + t]);
                cs[1][t] = c;
                hs1[t] = sigf(gat[192 + t]) * tanhf(c);
            }
            __syncthreads();
        }
        /* layer 2: K=64, input hs1 */
        {
            float a = bih2[t] + bhh2[t];
            const float4* wr = (const float4*)(wih2 + (size_t)t * 64);
            const float4* ur = (const float4*)(whh2 + (size_t)t * 64);
            #pragma unroll
            for (int k4 = 0; k4 < 16; ++k4) {
                float4 wv = wr[k4];
                float4 xv = *(const float4*)&hs1[4 * k4];
                a += wv.x*xv.x + wv.y*xv.y + wv.z*xv.z + wv.w*xv.w;
                float4 uv = ur[k4];
                float4 hv = *(const float4*)&hs2[4 * k4];
                a += uv.x*hv.x + uv.y*hv.y + uv.z*hv.z + uv.w*hv.w;
            }
            gat[t] = a;
            __syncthreads();
            if (t < 64) {
                float c = sigf(gat[64 + t]) * cs[2][t] + sigf(gat[t]) * tanhf(gat[128 + t]);
                cs[2][t] = c;
                hs2[t] = sigf(gat[192 + t]) * tanhf(c);
            }
            __syncthreads();
        }
        /* attention: scores over 256 threads */
        float mx = -1e30f;
        for (int p = t; p < cnt; p += 256) {
            const float* xr = x + (size_t)(n0 + p) * 64;
            float a = 0.0f;
            #pragma unroll
            for (int k4 = 0; k4 < 16; ++k4) {
                float4 xv = *(const float4*)&xr[4 * k4];
                float4 qv = *(const float4*)&hs2[4 * k4];
                a += xv.x*qv.x + xv.y*qv.y + xv.z*qv.z + xv.w*qv.w;
            }
            esc[p] = a;
            if (a > mx) mx = a;
        }
        gat[t] = mx;
        __syncthreads();
        for (int m = 128; m >= 1; m >>= 1) {
            if (t < m) { if (gat[t + m] > gat[t]) gat[t] = gat[t + m]; }
            __syncthreads();
        }
        mx = gat[0];
        __syncthreads();
        float z = 0.0f;
        for (int p = t; p < cnt; p += 256) {
            float a = expf(esc[p] - mx);
            esc[p] = a;
            z += a;
        }
        gat[t] = z;
        __syncthreads();
        for (int m = 128; m >= 1; m >>= 1) {
            if (t < m) gat[t] += gat[t + m];
            __syncthreads();
        }
        z = gat[0];
        float rz = (cnt > 0) ? 1.0f / z : 0.0f;
        /* readout: wave w handles rows p = w, w+4, ... (coalesced across lanes) */
        float rd = 0.0f;
        for (int p = w; p < cnt; p += 4)
            rd += x[(size_t)(n0 + p) * 64 + lane] * esc[p];
        red4[w][lane] = rd;
        __syncthreads();
        if (t < 64) {
            float r = (red4[0][t] + red4[1][t] + red4[2][t] + red4[3][t]) * rz;
            qs[t] = hs2[t];
            qs[64 + t] = r;
        }
        __syncthreads();
    }

    /* head: graphnorm -> fc1 -> bn -> relu -> fc2 -> relu */
    float v = (t < 128) ? qs[t] : 0.0f;
    gat[t] = v;
    __syncthreads();
    for (int m = 128; m >= 1; m >>= 1) {
        if (t < m) gat[t] += gat[t + m];
        __syncthreads();
    }
    float mu = gat[0] * (1.0f / 128.0f);
    __syncthreads();
    gat[t] = v * v;
    __syncthreads();
    for (int m = 128; m >= 1; m >>= 1) {
        if (t < m) gat[t] += gat[t + m];
        __syncthreads();
    }
    float var = gat[0] * (1.0f / 128.0f) - mu * mu;
    float rs = rsqrtf(var + 1e-5f);
    if (t < 128) scr[t] = (v - mu) * rs * gn_g[t] + gn_b[t];
    __syncthreads();
    if (t < 128) {
        float y = fc1_b[t];
        const float4* wr = (const float4*)(fc1_w + (size_t)t * 128);
        #pragma unroll
        for (int k4 = 0; k4 < 32; ++k4) {
            float4 wv = wr[k4];
            float4 gv = *(const float4*)&scr[4 * k4];
            y += wv.x*gv.x + wv.y*gv.y + wv.z*gv.z + wv.w*gv.w;
        }
        y = (y - bn_m[t]) * rsqrtf(bn_v[t] + 1e-5f) * bn_g[t] + bn_b[t];
        if (y < 0.0f) y = 0.0f;
        esc[t] = y;
    }
    __syncthreads();
    if (t < 64) {
        float o = fc2_b[t];
        const float4* wr = (const float4*)(fc2_w + (size_t)t * 128);
        #pragma unroll
        for (int k4 = 0; k4 < 32; ++k4) {
            float4 wv = wr[k4];
            float4 yv = *(const float4*)&esc[4 * k4];
            o += wv.x*yv.x + wv.y*yv.y + wv.z*yv.z + wv.w*yv.w;
        }
        if (!(o == o)) o = 999.0f;
        else if (o < 0.0f) o = 0.0f;
        out[(size_t)g * 64 + t] = o;
    }
}

extern "C" void kernel_launch(void* const* d_in, const int* in_sizes, int n_in,
                              void* d_out, int out_size, void* d_ws, size_t ws_size,
                              hipStream_t stream) {
    float* out = (float*)d_out;
    const int outBlocks = (KB * 64 + 255) / 256;

    if (n_in != 39) {
        GNNModule_9259949490279_kernel<<<outBlocks, 256, 0, stream>>>(out, 50.0f);
        return;
    }
    if (in_sizes[0] != KN * 64 || in_sizes[1] != KE || in_sizes[4] != KN) {
        GNNModule_9259949490279_kernel<<<outBlocks, 256, 0, stream>>>(out, 60.0f);
        return;
    }
    if (out_size != KB * 64) {
        GNNModule_9259949490279_kernel<<<outBlocks, 256, 0, stream>>>(out, 80.0f);
        return;
    }
    if (ws_size < O_END * 4) {
        GNNModule_9259949490279_kernel<<<outBlocks, 256, 0, stream>>>(out, 100.0f);
        return;
    }

    const float* atom = (const float*)d_in[0];
    const float* efeat = (const float*)d_in[1];
    const int* src = (const int*)d_in[2];
    const int* dst = (const int*)d_in[3];
    const int* gid = (const int*)d_in[4];
    const float* ew1[2] = {(const float*)d_in[5], (const float*)d_in[10]};
    const float* eb1[2] = {(const float*)d_in[6], (const float*)d_in[11]};
    const float* ew2[2] = {(const float*)d_in[7], (const float*)d_in[12]};
    const float* eb2[2] = {(const float*)d_in[8], (const float*)d_in[13]};
    const float* cb[2] = {(const float*)d_in[9], (const float*)d_in[14]};
    const float* ln_g = (const float*)d_in[15];
    const float* ln_b = (const float*)d_in[16];
    const float* wih0 = (const float*)d_in[17];
    const float* whh0 = (const float*)d_in[18];
    const float* bih0 = (const float*)d_in[19];
    const float* bhh0 = (const float*)d_in[20];
    const float* wih1 = (const float*)d_in[21];
    const float* whh1 = (const float*)d_in[22];
    const float* bih1 = (const float*)d_in[23];
    const float* bhh1 = (const float*)d_in[24];
    const float* wih2 = (const float*)d_in[25];
    const float* whh2 = (const float*)d_in[26];
    const float* bih2 = (const float*)d_in[27];
    const float* bhh2 = (const float*)d_in[28];
    const float* gn_g = (const float*)d_in[29];
    const float* gn_b = (const float*)d_in[30];
    const float* fc1_w = (const float*)d_in[31];
    const float* fc1_b = (const float*)d_in[32];
    const float* bn_g = (const float*)d_in[33];
    const float* bn_b = (const float*)d_in[34];
    const float* bn_m = (const float*)d_in[35];
    const float* bn_v = (const float*)d_in[36];
    const float* fc2_w = (const float*)d_in[37];
    const float* fc2_b = (const float*)d_in[38];

    float* wsf = (float*)d_ws;
    int* wsi = (int*)d_ws;
    float* buf0 = wsf + O_BUF0;
    float* buf1 = wsf + O_BUF1;
    float* deg = wsf + O_DEG;
    int* gcnt = wsi + O_GCNT;
    int* gstart = wsi + O_GST;
    int* flag = wsi + O_FLAG;
    float* Wb = wsf + O_WB;
    float* Ws = wsf + O_WS;
    float* cross = wsf + O_CROSS;
    int* rcnt = wsi + O_RCNT;
    int* region = wsi + O_REGN;

    k_zero<<<2048, 256, 0, stream>>>(wsf);
    k_fillm1<<<256, 256, 0, stream>>>(wsi);

    k_deg<<<KE / 256, 256, 0, stream>>>(dst, deg, flag);
    k_gcount<<<KN / 256, 256, 0, stream>>>(gid, gcnt, flag);
    k_gscan<<<1, 64, 0, stream>>>(gcnt, gstart);

    for (int l = 0; l < 2; ++l) {
        const float* xin = (l == 0) ? atom : buf0;
        float* sout = (l == 0) ? buf0 : buf1;
        int* hist = wsi + O_HIST + l * 64;
        int* cursor = wsi + O_CUR + l * 64;
        int* aoff = wsi + O_AOFF + l * 64;
        int* eorder = wsi + O_EORD + l * KEORD;
        int* rblk = wsi + O_RBLK + l * 1088;

        k_prep<<<1, 64, 0, stream>>>(ew1[l], eb1[l], cross, rcnt);
        k_mats<<<KNREG, 256, 0, stream>>>(ew1[l], eb1[l], ew2[l], eb2[l], cross, rcnt, Wb, Ws);
        k_region<<<KE / 256, 256, 0, stream>>>(efeat, cross, rcnt, region, hist);
        k_scan<<<1, 64, 0, stream>>>(hist, rcnt, aoff, rblk);
        k_scatidx<<<KE / 256, 256, 0, stream>>>(region, aoff, cursor, eorder);
        k_edge<<<KNBLK, 256, 0, stream>>>(xin, efeat, src, dst, Wb, Ws, rblk, eorder, sout);
        if (l == 0) {
            k_final0<<<KN * 64 / 256, 256, 0, stream>>>(buf0, deg, cb[0], flag);
        } else {
            k_final1ln<<<KN, 64, 0, stream>>>(buf1, deg, cb[1], ln_g, ln_b, flag);
        }
    }

    k_s2s<<<KB, 256, 0, stream>>>(buf1, gstart,
        wih0, whh0, bih0, bhh0,
        wih1, whh1, bih1, bhh1,
        wih2, whh2, bih2, bhh2,
        gn_g, gn_b, fc1_w, fc1_b, bn_g, bn_b, bn_m, bn_v, fc2_w, fc2_b,
        out, flag);

    k_post<<<outBlocks, 256, 0, stream>>>(flag, out);
}

// Round 11
// 477.223 us; speedup vs baseline: 48.5760x; 3.6955x over previous
//
#include <hip/hip_runtime.h>

#define KN 32768
#define KE 65536
#define KB 512
#define KEPB 64
#define KNREG 33
#define KEORD (KE + KNREG * KEPB)   /* 67648 padded sorted-edge slots */
#define KNBLK (KEORD / KEPB)        /* 1057 edge blocks */

/* ---------------- workspace element offsets ---------------- */
/* zero-init zone */
#define O_BUF0 ((size_t)0)
#define O_BUF1 (O_BUF0 + (size_t)KN * 64)
#define O_DEG  (O_BUF1 + (size_t)KN * 64)
#define O_GCNT (O_DEG + KN)
#define O_GST  (O_GCNT + KB)
#define O_HIST (O_GST + KB + 8)          /* [2][64] */
#define O_CUR  (O_HIST + 128)            /* [2][64] */
#define O_FLAG (O_CUR + 128)
#define O_ZEND (O_FLAG + 64)
/* -1-init zone */
#define O_EORD ((O_ZEND + 63) & ~(size_t)63)    /* [2][KEORD] */
#define O_RBLK (O_EORD + 2 * (size_t)KEORD)     /* [2][1088] */
#define O_FEND (O_RBLK + 2 * 1088)
/* no-init zone (fully written before read) */
#define O_WB   ((O_FEND + 63) & ~(size_t)63)    /* [33][4096] */
#define O_WS   (O_WB + (size_t)KNREG * 4096)
#define O_CROSS (O_WS + (size_t)KNREG * 4096)   /* [32] */
#define O_RCNT (O_CROSS + 64)
#define O_AOFF (O_RCNT + 64)                     /* [2][64] */
#define O_REGN (O_AOFF + 128)                    /* [E] */
#define O_END  (O_REGN + KE)

__device__ float sigf(float x) { return 1.0f / (1.0f + expf(-x)); }

/* diagnostic fill (f32 output) */
extern "C" __global__ void GNNModule_9259949490279_kernel(float* out, float v) {
    int i = blockIdx.x * 256 + threadIdx.x;
    if (i < KB * 64) out[i] = v;
}

extern "C" __global__ void k_post(const int* flag, float* out) {
    int f = flag[0];
    if (f == 0) return;
    int i = blockIdx.x * 256 + threadIdx.x;
    if (i < KB * 64) out[i] = 300.0f + (float)f;
}

extern "C" __global__ void k_zero(float* ws) {
    size_t i = (size_t)blockIdx.x * 256 + threadIdx.x;
    size_t stride = (size_t)gridDim.x * 256;
    for (size_t p = i; p < O_ZEND; p += stride) ws[p] = 0.0f;
}

extern "C" __global__ void k_fillm1(int* ws) {
    size_t i = (size_t)blockIdx.x * 256 + threadIdx.x;
    size_t stride = (size_t)gridDim.x * 256;
    for (size_t p = O_EORD + i; p < O_FEND; p += stride) ws[p] = -1;
}

extern "C" __global__ void k_deg(const int* dst, float* deg, int* flag) {
    int e = blockIdx.x * 256 + threadIdx.x;
    if (e >= KE) return;
    int d = dst[e];
    if ((unsigned)d >= (unsigned)KN) { atomicOr(flag, 1); d = 0; }
    atomicAdd(&deg[d], 1.0f);
}

extern "C" __global__ void k_gcount(const int* gid, int* gcnt, int* flag) {
    int n = blockIdx.x * 256 + threadIdx.x;
    if (n >= KN) return;
    int g = gid[n];
    if ((unsigned)g >= (unsigned)KB) { atomicOr(flag, 2); g = 0; }
    atomicAdd(&gcnt[g], 1);
}

extern "C" __global__ void k_gscan(const int* gcnt, int* gstart) {
    __shared__ int part[64];
    __shared__ int pre[64];
    int t = threadIdx.x;
    int v[8];
    int s = 0;
    int base = t * 8;
    for (int j = 0; j < 8; ++j) { v[j] = gcnt[base + j]; s += v[j]; }
    part[t] = s;
    __syncthreads();
    if (t == 0) {
        int run = 0;
        for (int i = 0; i < 64; ++i) { pre[i] = run; run += part[i]; }
    }
    __syncthreads();
    int run = pre[t];
    for (int j = 0; j < 8; ++j) { gstart[base + j] = run; run += v[j]; }
    if (t == 63) gstart[KB] = run;
}

/* ---- region machinery: exact piecewise-linear edge MLP ---- */
extern "C" __global__ void k_prep(const float* ew1, const float* eb1,
                                  float* cross, int* rcnt) {
    if (threadIdx.x != 0 || blockIdx.x != 0) return;
    float cl[32];
    int n = 0;
    for (int k = 0; k < 32; ++k) {
        float a = ew1[k], b = eb1[k];
        if (a != 0.0f) {
            float tt = -b / a;
            if (tt > 0.0f && tt < 1.0f) cl[n++] = tt;
        }
    }
    for (int i = 1; i < n; ++i) {
        float v = cl[i];
        int j = i - 1;
        while (j >= 0 && cl[j] > v) { cl[j + 1] = cl[j]; --j; }
        cl[j + 1] = v;
    }
    for (int i = 0; i < n; ++i) cross[i] = cl[i];
    *rcnt = n;
}

extern "C" __global__ __launch_bounds__(256) void k_mats(
    const float* ew1, const float* eb1, const float* ew2, const float* eb2,
    const float* cross, const int* rcnt, float* Wb, float* Ws) {
    int r = blockIdx.x;
    int n = *rcnt;
    if (r > n) return;
    float lo = (r == 0) ? 0.0f : cross[r - 1];
    float hi = (r == n) ? 1.0f : cross[r];
    float mid = 0.5f * (lo + hi);
    __shared__ float mw[32], mb[32];
    int t = threadIdx.x;
    if (t < 32) {
        bool act = (mid * ew1[t] + eb1[t]) > 0.0f;
        mw[t] = act ? ew1[t] : 0.0f;
        mb[t] = act ? eb1[t] : 0.0f;
    }
    __syncthreads();
    #pragma unroll
    for (int j = 0; j < 16; ++j) {
        int idx = j * 256 + t;
        float as = 0.0f, ab = eb2[idx];
        #pragma unroll
        for (int k4 = 0; k4 < 8; ++k4) {
            float4 w2 = *(const float4*)&ew2[(size_t)idx * 32 + 4 * k4];
            as += mw[4*k4+0]*w2.x + mw[4*k4+1]*w2.y + mw[4*k4+2]*w2.z + mw[4*k4+3]*w2.w;
            ab += mb[4*k4+0]*w2.x + mb[4*k4+1]*w2.y + mb[4*k4+2]*w2.z + mb[4*k4+3]*w2.w;
        }
        Wb[(size_t)r * 4096 + idx] = ab;
        Ws[(size_t)r * 4096 + idx] = as;
    }
}

/* LDS histogram -> <=33 global atomics per block (was 65536 over 33 addrs) */
extern "C" __global__ void k_region(const float* ef, const float* cross,
                                    const int* rcnt, int* region, int* hist) {
    __shared__ float lcross[32];
    __shared__ int lh[64];
    __shared__ int ln;
    int t = threadIdx.x;
    if (t == 0) ln = *rcnt;
    if (t < 64) lh[t] = 0;
    if (t >= 32 && t < 64) lcross[t - 32] = 0.0f;
    __syncthreads();
    if (t < 32 && t < ln) lcross[t] = cross[t];
    __syncthreads();
    int e = blockIdx.x * 256 + t;
    float f = ef[e];
    int n = ln, r = 0;
    for (int j = 0; j < n; ++j) r += (f > lcross[j]) ? 1 : 0;
    region[e] = r;
    atomicAdd(&lh[r], 1);
    __syncthreads();
    if (t < 64 && lh[t] > 0) atomicAdd(&hist[t], lh[t]);
}

extern "C" __global__ void k_scan(const int* hist, const int* rcnt,
                                  int* aoff, int* rblk) {
    if (threadIdx.x != 0 || blockIdx.x != 0) return;
    int R = *rcnt + 1;
    int base = 0;
    for (int r = 0; r < R; ++r) {
        aoff[r] = base * KEPB;
        int nb = (hist[r] + KEPB - 1) / KEPB;
        for (int j = 0; j < nb; ++j) rblk[base + j] = r;
        base += nb;
    }
}

/* local LDS rank + one chunk-reserving global atomic per (block,region) */
extern "C" __global__ void k_scatidx(const int* region, const int* aoff,
                                     int* cursor, int* eorder) {
    __shared__ int lcnt[64];
    __shared__ int lbase[64];
    int t = threadIdx.x;
    if (t < 64) lcnt[t] = 0;
    __syncthreads();
    int e = blockIdx.x * 256 + t;
    int r = region[e];
    int lr = atomicAdd(&lcnt[r], 1);
    __syncthreads();
    if (t < 64 && lcnt[t] > 0) lbase[t] = atomicAdd(&cursor[t], lcnt[t]);
    __syncthreads();
    eorder[aoff[r] + lbase[r] + lr] = e;
}

/* ---- edge message + scatter (HW-verified round 9, kept verbatim) ---- */
extern "C" __global__ __launch_bounds__(256) void k_edge(
    const float* x, const float* efeat, const int* src, const int* dst,
    const float* Wb, const float* Ws, const int* rblk, const int* eorder,
    float* sbuf) {
    __shared__ __align__(16) float mbuf[4096];
    __shared__ __align__(16) float msuf[4096];
    __shared__ __align__(16) float xs[4][16][64];
    int b = blockIdx.x;
    int r = rblk[b];
    if (r < 0) return;
    int t = threadIdx.x;
    const float4* gb = (const float4*)(Wb + (size_t)r * 4096);
    const float4* gs = (const float4*)(Ws + (size_t)r * 4096);
    float4* lb = (float4*)mbuf;
    float4* ls = (float4*)msuf;
    #pragma unroll
    for (int j = 0; j < 4; ++j) {
        lb[t + 256 * j] = gb[t + 256 * j];
        ls[t + 256 * j] = gs[t + 256 * j];
    }
    __syncthreads();
    int w = t >> 6, lane = t & 63;
    int base = b * KEPB + w * 16;
    int eid = (lane < 16) ? eorder[base + lane] : -1;
    float efl = 0.0f;
    int srl = 0, dsl = 0;
    if (eid >= 0) { efl = efeat[eid]; srl = src[eid]; dsl = dst[eid]; }
    unsigned long long vm = __ballot(eid >= 0);
    if ((vm & 0xFFFFull) == 0ull) return;
    float ef[16];
    int dv[16];
    #pragma unroll
    for (int s = 0; s < 16; ++s) {
        ef[s] = __shfl(efl, s);
        int sv = __shfl(srl, s);
        dv[s] = __shfl(dsl, s);
        xs[w][s][lane] = x[(size_t)sv * 64 + lane];
    }
    float acc[16];
    #pragma unroll
    for (int s = 0; s < 16; ++s) acc[s] = 0.0f;
    #pragma unroll 1
    for (int i4 = 0; i4 < 16; ++i4) {
        float wb0 = mbuf[(i4 * 4 + 0) * 64 + lane], ws0 = msuf[(i4 * 4 + 0) * 64 + lane];
        float wb1 = mbuf[(i4 * 4 + 1) * 64 + lane], ws1 = msuf[(i4 * 4 + 1) * 64 + lane];
        float wb2 = mbuf[(i4 * 4 + 2) * 64 + lane], ws2 = msuf[(i4 * 4 + 2) * 64 + lane];
        float wb3 = mbuf[(i4 * 4 + 3) * 64 + lane], ws3 = msuf[(i4 * 4 + 3) * 64 + lane];
        #pragma unroll
        for (int j = 0; j < 16; ++j) {
            float4 xv = *(const float4*)&xs[w][j][i4 * 4];
            acc[j] = fmaf(xv.x, fmaf(ef[j], ws0, wb0), acc[j]);
            acc[j] = fmaf(xv.y, fmaf(ef[j], ws1, wb1), acc[j]);
            acc[j] = fmaf(xv.z, fmaf(ef[j], ws2, wb2), acc[j]);
            acc[j] = fmaf(xv.w, fmaf(ef[j], ws3, wb3), acc[j]);
        }
    }
    #pragma unroll
    for (int j = 0; j < 16; ++j) {
        if ((vm >> j) & 1ull) atomicAdd(&sbuf[(size_t)dv[j] * 64 + lane], acc[j]);
    }
}

extern "C" __global__ void k_final0(float* s, const float* deg, const float* cb, int* flag) {
    int idx = blockIdx.x * 256 + threadIdx.x;
    int n = idx >> 6;
    int o = idx & 63;
    float d = deg[n];
    if (d < 1.0f) d = 1.0f;
    float v = s[idx] / d + cb[o];
    if (v < 0.0f) v = 0.0f;
    if (!(v == v)) { v = 0.0f; atomicOr(flag, 32); }
    s[idx] = v;
}

extern "C" __global__ void k_final1ln(float* s, const float* deg, const float* cb,
                                      const float* lg, const float* lb, int* flag) {
    __shared__ float red[64];
    int t = threadIdx.x;
    int n = blockIdx.x;
    float d = deg[n];
    if (d < 1.0f) d = 1.0f;
    float v = s[(size_t)n * 64 + t] / d + cb[t];
    if (v < 0.0f) v = 0.0f;
    red[t] = v;
    __syncthreads();
    for (int m = 32; m >= 1; m >>= 1) {
        if (t < m) red[t] += red[t + m];
        __syncthreads();
    }
    float mu = red[0] * (1.0f / 64.0f);
    __syncthreads();
    red[t] = v * v;
    __syncthreads();
    for (int m = 32; m >= 1; m >>= 1) {
        if (t < m) red[t] += red[t + m];
        __syncthreads();
    }
    float var = red[0] * (1.0f / 64.0f) - mu * mu;
    float rs = rsqrtf(var + 1e-5f);
    float r = (v - mu) * rs * lg[t] + lb[t];
    if (!(r == r)) { r = 0.0f; atomicOr(flag, 8); }
    s[(size_t)n * 64 + t] = r;
}

/* ---- Set2Set + head (HW-verified round 10, kept verbatim) ---- */
extern "C" __global__ __launch_bounds__(256) void k_s2s(
    const float* x, const int* gstart,
    const float* wih0, const float* whh0, const float* bih0, const float* bhh0,
    const float* wih1, const float* whh1, const float* bih1, const float* bhh1,
    const float* wih2, const float* whh2, const float* bih2, const float* bhh2,
    const float* gn_g, const float* gn_b,
    const float* fc1_w, const float* fc1_b,
    const float* bn_g, const float* bn_b, const float* bn_m, const float* bn_v,
    const float* fc2_w, const float* fc2_b,
    float* out, int* flag) {
    __shared__ __align__(16) float qs[128];
    __shared__ __align__(16) float hs0[64];
    __shared__ __align__(16) float hs1[64];
    __shared__ __align__(16) float hs2[64];
    __shared__ __align__(16) float cs[3][64];
    __shared__ __align__(16) float gat[256];
    __shared__ __align__(16) float esc[1024];
    __shared__ __align__(16) float red4[4][64];
    __shared__ __align__(16) float scr[128];
    int t = threadIdx.x;           /* 0..255 */
    int g = blockIdx.x;
    int w = t >> 6, lane = t & 63;

    if (t < 128) qs[t] = 0.0f;
    if (t < 64) {
        hs0[t] = 0.0f; hs1[t] = 0.0f; hs2[t] = 0.0f;
        cs[0][t] = 0.0f; cs[1][t] = 0.0f; cs[2][t] = 0.0f;
    }
    __syncthreads();

    int n0 = gstart[g];
    int n1 = gstart[g + 1];
    if (n0 < 0) n0 = 0;
    if (n0 > KN) n0 = KN;
    if (n1 < n0) n1 = n0;
    if (n1 > KN) n1 = KN;
    int cnt = n1 - n0;
    if (cnt > 1024) { cnt = 1024; if (t == 0) atomicOr(flag, 16); }

    for (int it = 0; it < 6; ++it) {
        {
            float a = bih0[t] + bhh0[t];
            const float4* wr = (const float4*)(wih0 + (size_t)t * 128);
            #pragma unroll
            for (int k4 = 0; k4 < 32; ++k4) {
                float4 wv = wr[k4];
                float4 xv = *(const float4*)&qs[4 * k4];
                a += wv.x*xv.x + wv.y*xv.y + wv.z*xv.z + wv.w*xv.w;
            }
            const float4* ur = (const float4*)(whh0 + (size_t)t * 64);
            #pragma unroll
            for (int k4 = 0; k4 < 16; ++k4) {
                float4 wv = ur[k4];
                float4 hv = *(const float4*)&hs0[4 * k4];
                a += wv.x*hv.x + wv.y*hv.y + wv.z*hv.z + wv.w*hv.w;
            }
            gat[t] = a;
            __syncthreads();
            if (t < 64) {
                float c = sigf(gat[64 + t]) * cs[0][t] + sigf(gat[t]) * tanhf(gat[128 + t]);
                cs[0][t] = c;
                hs0[t] = sigf(gat[192 + t]) * tanhf(c);
            }
            __syncthreads();
        }
        {
            float a = bih1[t] + bhh1[t];
            const float4* wr = (const float4*)(wih1 + (size_t)t * 64);
            const float4* ur = (const float4*)(whh1 + (size_t)t * 64);
            #pragma unroll
            for (int k4 = 0; k4 < 16; ++k4) {
                float4 wv = wr[k4];
                float4 xv = *(const float4*)&hs0[4 * k4];
                a += wv.x*xv.x + wv.y*xv.y + wv.z*xv.z + wv.w*xv.w;
                float4 uv = ur[k4];
                float4 hv = *(const float4*)&hs1[4 * k4];
                a += uv.x*hv.x + uv.y*hv.y + uv.z*hv.z + uv.w*hv.w;
            }
            gat[t] = a;
            __syncthreads();
            if (t < 64) {
                float c = sigf(gat[64 + t]) * cs[1][t] + sigf(gat[t]) * tanhf(gat[128 + t]);
                cs[1][t] = c;
                hs1[t] = sigf(gat[192 + t]) * tanhf(c);
            }
            __syncthreads();
        }
        {
            float a = bih2[t] + bhh2[t];
            const float4* wr = (const float4*)(wih2 + (size_t)t * 64);
            const float4* ur = (const float4*)(whh2 + (size_t)t * 64);
            #pragma unroll
            for (int k4 = 0; k4 < 16; ++k4) {
                float4 wv = wr[k4];
                float4 xv = *(const float4*)&hs1[4 * k4];
                a += wv.x*xv.x + wv.y*xv.y + wv.z*xv.z + wv.w*xv.w;
                float4 uv = ur[k4];
                float4 hv = *(const float4*)&hs2[4 * k4];
                a += uv.x*hv.x + uv.y*hv.y + uv.z*hv.z + uv.w*hv.w;
            }
            gat[t] = a;
            __syncthreads();
            if (t < 64) {
                float c = sigf(gat[64 + t]) * cs[2][t] + sigf(gat[t]) * tanhf(gat[128 + t]);
                cs[2][t] = c;
                hs2[t] = sigf(gat[192 + t]) * tanhf(c);
            }
            __syncthreads();
        }
        float mx = -1e30f;
        for (int p = t; p < cnt; p += 256) {
            const float* xr = x + (size_t)(n0 + p) * 64;
            float a = 0.0f;
            #pragma unroll
            for (int k4 = 0; k4 < 16; ++k4) {
                float4 xv = *(const float4*)&xr[4 * k4];
                float4 qv = *(const float4*)&hs2[4 * k4];
                a += xv.x*qv.x + xv.y*qv.y + xv.z*qv.z + xv.w*qv.w;
            }
            esc[p] = a;
            if (a > mx) mx = a;
        }
        gat[t] = mx;
        __syncthreads();
        for (int m = 128; m >= 1; m >>= 1) {
            if (t < m) { if (gat[t + m] > gat[t]) gat[t] = gat[t + m]; }
            __syncthreads();
        }
        mx = gat[0];
        __syncthreads();
        float z = 0.0f;
        for (int p = t; p < cnt; p += 256) {
            float a = expf(esc[p] - mx);
            esc[p] = a;
            z += a;
        }
        gat[t] = z;
        __syncthreads();
        for (int m = 128; m >= 1; m >>= 1) {
            if (t < m) gat[t] += gat[t + m];
            __syncthreads();
        }
        z = gat[0];
        float rz = (cnt > 0) ? 1.0f / z : 0.0f;
        float rd = 0.0f;
        for (int p = w; p < cnt; p += 4)
            rd += x[(size_t)(n0 + p) * 64 + lane] * esc[p];
        red4[w][lane] = rd;
        __syncthreads();
        if (t < 64) {
            float r = (red4[0][t] + red4[1][t] + red4[2][t] + red4[3][t]) * rz;
            qs[t] = hs2[t];
            qs[64 + t] = r;
        }
        __syncthreads();
    }

    float v = (t < 128) ? qs[t] : 0.0f;
    gat[t] = v;
    __syncthreads();
    for (int m = 128; m >= 1; m >>= 1) {
        if (t < m) gat[t] += gat[t + m];
        __syncthreads();
    }
    float mu = gat[0] * (1.0f / 128.0f);
    __syncthreads();
    gat[t] = v * v;
    __syncthreads();
    for (int m = 128; m >= 1; m >>= 1) {
        if (t < m) gat[t] += gat[t + m];
        __syncthreads();
    }
    float var = gat[0] * (1.0f / 128.0f) - mu * mu;
    float rs = rsqrtf(var + 1e-5f);
    if (t < 128) scr[t] = (v - mu) * rs * gn_g[t] + gn_b[t];
    __syncthreads();
    if (t < 128) {
        float y = fc1_b[t];
        const float4* wr = (const float4*)(fc1_w + (size_t)t * 128);
        #pragma unroll
        for (int k4 = 0; k4 < 32; ++k4) {
            float4 wv = wr[k4];
            float4 gv = *(const float4*)&scr[4 * k4];
            y += wv.x*gv.x + wv.y*gv.y + wv.z*gv.z + wv.w*gv.w;
        }
        y = (y - bn_m[t]) * rsqrtf(bn_v[t] + 1e-5f) * bn_g[t] + bn_b[t];
        if (y < 0.0f) y = 0.0f;
        esc[t] = y;
    }
    __syncthreads();
    if (t < 64) {
        float o = fc2_b[t];
        const float4* wr = (const float4*)(fc2_w + (size_t)t * 128);
        #pragma unroll
        for (int k4 = 0; k4 < 32; ++k4) {
            float4 wv = wr[k4];
            float4 yv = *(const float4*)&esc[4 * k4];
            o += wv.x*yv.x + wv.y*yv.y + wv.z*yv.z + wv.w*yv.w;
        }
        if (!(o == o)) o = 999.0f;
        else if (o < 0.0f) o = 0.0f;
        out[(size_t)g * 64 + t] = o;
    }
}

extern "C" void kernel_launch(void* const* d_in, const int* in_sizes, int n_in,
                              void* d_out, int out_size, void* d_ws, size_t ws_size,
                              hipStream_t stream) {
    float* out = (float*)d_out;
    const int outBlocks = (KB * 64 + 255) / 256;

    if (n_in != 39) {
        GNNModule_9259949490279_kernel<<<outBlocks, 256, 0, stream>>>(out, 50.0f);
        return;
    }
    if (in_sizes[0] != KN * 64 || in_sizes[1] != KE || in_sizes[4] != KN) {
        GNNModule_9259949490279_kernel<<<outBlocks, 256, 0, stream>>>(out, 60.0f);
        return;
    }
    if (out_size != KB * 64) {
        GNNModule_9259949490279_kernel<<<outBlocks, 256, 0, stream>>>(out, 80.0f);
        return;
    }
    if (ws_size < O_END * 4) {
        GNNModule_9259949490279_kernel<<<outBlocks, 256, 0, stream>>>(out, 100.0f);
        return;
    }

    const float* atom = (const float*)d_in[0];
    const float* efeat = (const float*)d_in[1];
    const int* src = (const int*)d_in[2];
    const int* dst = (const int*)d_in[3];
    const int* gid = (const int*)d_in[4];
    const float* ew1[2] = {(const float*)d_in[5], (const float*)d_in[10]};
    const float* eb1[2] = {(const float*)d_in[6], (const float*)d_in[11]};
    const float* ew2[2] = {(const float*)d_in[7], (const float*)d_in[12]};
    const float* eb2[2] = {(const float*)d_in[8], (const float*)d_in[13]};
    const float* cb[2] = {(const float*)d_in[9], (const float*)d_in[14]};
    const float* ln_g = (const float*)d_in[15];
    const float* ln_b = (const float*)d_in[16];
    const float* wih0 = (const float*)d_in[17];
    const float* whh0 = (const float*)d_in[18];
    const float* bih0 = (const float*)d_in[19];
    const float* bhh0 = (const float*)d_in[20];
    const float* wih1 = (const float*)d_in[21];
    const float* whh1 = (const float*)d_in[22];
    const float* bih1 = (const float*)d_in[23];
    const float* bhh1 = (const float*)d_in[24];
    const float* wih2 = (const float*)d_in[25];
    const float* whh2 = (const float*)d_in[26];
    const float* bih2 = (const float*)d_in[27];
    const float* bhh2 = (const float*)d_in[28];
    const float* gn_g = (const float*)d_in[29];
    const float* gn_b = (const float*)d_in[30];
    const float* fc1_w = (const float*)d_in[31];
    const float* fc1_b = (const float*)d_in[32];
    const float* bn_g = (const float*)d_in[33];
    const float* bn_b = (const float*)d_in[34];
    const float* bn_m = (const float*)d_in[35];
    const float* bn_v = (const float*)d_in[36];
    const float* fc2_w = (const float*)d_in[37];
    const float* fc2_b = (const float*)d_in[38];

    float* wsf = (float*)d_ws;
    int* wsi = (int*)d_ws;
    float* buf0 = wsf + O_BUF0;
    float* buf1 = wsf + O_BUF1;
    float* deg = wsf + O_DEG;
    int* gcnt = wsi + O_GCNT;
    int* gstart = wsi + O_GST;
    int* flag = wsi + O_FLAG;
    float* Wb = wsf + O_WB;
    float* Ws = wsf + O_WS;
    float* cross = wsf + O_CROSS;
    int* rcnt = wsi + O_RCNT;
    int* region = wsi + O_REGN;

    k_zero<<<2048, 256, 0, stream>>>(wsf);
    k_fillm1<<<256, 256, 0, stream>>>(wsi);

    k_deg<<<KE / 256, 256, 0, stream>>>(dst, deg, flag);
    k_gcount<<<KN / 256, 256, 0, stream>>>(gid, gcnt, flag);
    k_gscan<<<1, 64, 0, stream>>>(gcnt, gstart);

    for (int l = 0; l < 2; ++l) {
        const float* xin = (l == 0) ? atom : buf0;
        float* sout = (l == 0) ? buf0 : buf1;
        int* hist = wsi + O_HIST + l * 64;
        int* cursor = wsi + O_CUR + l * 64;
        int* aoff = wsi + O_AOFF + l * 64;
        int* eorder = wsi + O_EORD + l * KEORD;
        int* rblk = wsi + O_RBLK + l * 1088;

        k_prep<<<1, 64, 0, stream>>>(ew1[l], eb1[l], cross, rcnt);
        k_mats<<<KNREG, 256, 0, stream>>>(ew1[l], eb1[l], ew2[l], eb2[l], cross, rcnt, Wb, Ws);
        k_region<<<KE / 256, 256, 0, stream>>>(efeat, cross, rcnt, region, hist);
        k_scan<<<1, 64, 0, stream>>>(hist, rcnt, aoff, rblk);
        k_scatidx<<<KE / 256, 256, 0, stream>>>(region, aoff, cursor, eorder);
        k_edge<<<KNBLK, 256, 0, stream>>>(xin, efeat, src, dst, Wb, Ws, rblk, eorder, sout);
        if (l == 0) {
            k_final0<<<KN * 64 / 256, 256, 0, stream>>>(buf0, deg, cb[0], flag);
        } else {
            k_final1ln<<<KN, 64, 0, stream>>>(buf1, deg, cb[1], ln_g, ln_b, flag);
        }
    }

    k_s2s<<<KB, 256, 0, stream>>>(buf1, gstart,
        wih0, whh0, bih0, bhh0,
        wih1, whh1, bih1, bhh1,
        wih2, whh2, bih2, bhh2,
        gn_g, gn_b, fc1_w, fc1_b, bn_g, bn_b, bn_m, bn_v, fc2_w, fc2_b,
        out, flag);

    k_post<<<outBlocks, 256, 0, stream>>>(flag, out);
}